// Round 2
// baseline (361.969 us; speedup 1.0000x reference)
//
#include <hip/hip_runtime.h>
#include <hip/hip_bf16.h>
#include <stdint.h>

#define S_LEN 2048
#define BATCH 2
#define EMB   1024
#define NH    16
#define HD    64

typedef __bf16 bf16x8 __attribute__((ext_vector_type(8)));
typedef float  f32x4  __attribute__((ext_vector_type(4)));
typedef unsigned short ushort8 __attribute__((ext_vector_type(8)));

__device__ __forceinline__ unsigned short f2bf(float f) {
  unsigned int u = __float_as_uint(f);
  u += 0x7fffu + ((u >> 16) & 1u);
  return (unsigned short)(u >> 16);
}

__device__ __forceinline__ ushort8 cvt8(const float4 a, const float4 b) {
  ushort8 o;
  o[0]=f2bf(a.x); o[1]=f2bf(a.y); o[2]=f2bf(a.z); o[3]=f2bf(a.w);
  o[4]=f2bf(b.x); o[5]=f2bf(b.y); o[6]=f2bf(b.z); o[7]=f2bf(b.w);
  return o;
}

#define GLOAD16(g, l) __builtin_amdgcn_global_load_lds( \
    (const __attribute__((address_space(1))) void*)(g),  \
    (__attribute__((address_space(3))) void*)(l), 16, 0, 0)

// ---------------- QKV projection for one batch (fused fp32->bf16 staging) ----
// A = x_b (fp32, row stride 2048), B^T = w (fp32, [1024][1024])
// C[i][f] = sum_e x_b[i][e] * w[f][e]; z=0:Q(scaled+bias) 1:K 2:V(transposed)
__global__ __launch_bounds__(256) void k_qkv(
    const float* __restrict__ xb,
    const float* __restrict__ wq, const float* __restrict__ wk,
    const float* __restrict__ wv,
    const float* __restrict__ bq, const float* __restrict__ bk,
    const float* __restrict__ bv,
    unsigned short* __restrict__ Qb, unsigned short* __restrict__ Kb,
    unsigned short* __restrict__ Vtb)
{
  __shared__ unsigned short Al[128*32];
  __shared__ unsigned short Bl[128*32];
  const int tid = threadIdx.x;
  const int z  = blockIdx.z;
  const int m0 = blockIdx.x * 128;
  const int n0 = blockIdx.y * 128;
  const int w = tid >> 6, lane = tid & 63;
  const int wr = w >> 1, wc = w & 1;
  const int lr = lane & 15, lhi = lane >> 4;
  const float* wz = (z==0) ? wq : ((z==1) ? wk : wv);

  f32x4 acc[4][4];
#pragma unroll
  for (int m=0;m<4;++m)
#pragma unroll
    for (int n=0;n<4;++n) acc[m][n] = (f32x4){0.f,0.f,0.f,0.f};

  for (int k0 = 0; k0 < EMB; k0 += 32) {
    float4 a0[2], a1[2], b0[2], b1[2];
#pragma unroll
    for (int j = 0; j < 2; ++j) {
      const int c   = j*256 + tid;
      const int row = c >> 2;
      const int col = (c & 3) << 3;
      const float* ap = xb + (size_t)(m0+row)*(BATCH*EMB) + k0 + col;
      const float* bp = wz + (size_t)(n0+row)*EMB + k0 + col;
      a0[j] = *(const float4*)ap;  a1[j] = *(const float4*)(ap+4);
      b0[j] = *(const float4*)bp;  b1[j] = *(const float4*)(bp+4);
    }
    __syncthreads();
#pragma unroll
    for (int j = 0; j < 2; ++j) {
      const int c   = j*256 + tid;
      const int row = c >> 2;
      const int col = (c & 3) << 3;
      *(ushort8*)&Al[row*32 + col] = cvt8(a0[j], a1[j]);
      *(ushort8*)&Bl[row*32 + col] = cvt8(b0[j], b1[j]);
    }
    __syncthreads();
    bf16x8 af[4], bfr[4];
#pragma unroll
    for (int m=0;m<4;++m) af[m]  = *(const bf16x8*)&Al[(wr*64 + m*16 + lr)*32 + lhi*8];
#pragma unroll
    for (int n=0;n<4;++n) bfr[n] = *(const bf16x8*)&Bl[(wc*64 + n*16 + lr)*32 + lhi*8];
#pragma unroll
    for (int m=0;m<4;++m)
#pragma unroll
      for (int n=0;n<4;++n)
        acc[m][n] = __builtin_amdgcn_mfma_f32_16x16x32_bf16(af[m], bfr[n], acc[m][n], 0,0,0);
  }

  const float scale = (z==0) ? 0.125f : 1.0f;   // D^-0.5
  const float* bias = (z==0) ? bq : ((z==1) ? bk : bv);
#pragma unroll
  for (int m=0;m<4;++m)
#pragma unroll
    for (int n=0;n<4;++n)
#pragma unroll
      for (int r=0;r<4;++r) {
        const int i    = m0 + wr*64 + m*16 + lhi*4 + r;   // seq pos
        const int fcol = n0 + wc*64 + n*16 + lr;          // f = h*64+d
        const float v = (acc[m][n][r] + bias[fcol]) * scale;
        const unsigned short ov = f2bf(v);
        const int h = fcol >> 6, d = fcol & 63;
        if (z == 0)      Qb [((size_t)h*S_LEN + i)*HD + d] = ov;
        else if (z == 1) Kb [((size_t)h*S_LEN + i)*HD + d] = ov;
        else             Vtb[((size_t)h*HD + d)*S_LEN + i] = ov;
      }
}

// ---------------- causal flash attention, one batch ----------------
// grid (S/128, NH), 4 waves/block, each wave owns 32 q-rows independently
__global__ __launch_bounds__(256) void k_attn(
    const unsigned short* __restrict__ Q,
    const unsigned short* __restrict__ K,
    const unsigned short* __restrict__ Vt,
    unsigned short* __restrict__ ctx)
{
  __shared__ unsigned short Pl[4*2048];
  const int tid = threadIdx.x;
  const int w = tid >> 6, lane = tid & 63;
  const int lr = lane & 15, lhi = lane >> 4;
  const int h = blockIdx.y;
  const int q0 = blockIdx.x*128 + w*32;
  const unsigned short* Qh = Q  + (size_t)h*S_LEN*HD;
  const unsigned short* Kh = K  + (size_t)h*S_LEN*HD;
  const unsigned short* Vh = Vt + (size_t)h*HD*S_LEN;
  unsigned short* Pw = Pl + w*2048;

  bf16x8 qf[2][2];
#pragma unroll
  for (int m=0;m<2;++m)
#pragma unroll
    for (int kf=0;kf<2;++kf)
      qf[m][kf] = *(const bf16x8*)&Qh[(size_t)(q0 + m*16 + lr)*HD + kf*32 + lhi*8];

  f32x4 o[2][4];
  float rm[2][4], rl[2][4];
#pragma unroll
  for (int m=0;m<2;++m) {
#pragma unroll
    for (int n=0;n<4;++n) o[m][n] = (f32x4){0.f,0.f,0.f,0.f};
#pragma unroll
    for (int r=0;r<4;++r) { rm[m][r] = -3.0e38f; rl[m][r] = 0.f; }
  }

  const int tend = (q0 + 31)/64 + 1;
  for (int t = 0; t < tend; ++t) {
    const int kv0 = t*64;
    f32x4 s[2][4];
#pragma unroll
    for (int m=0;m<2;++m)
#pragma unroll
      for (int n=0;n<4;++n) s[m][n] = (f32x4){0.f,0.f,0.f,0.f};

#pragma unroll
    for (int n=0;n<4;++n)
#pragma unroll
      for (int kf=0;kf<2;++kf) {
        const bf16x8 kfr = *(const bf16x8*)&Kh[(size_t)(kv0 + n*16 + lr)*HD + kf*32 + lhi*8];
#pragma unroll
        for (int m=0;m<2;++m)
          s[m][n] = __builtin_amdgcn_mfma_f32_16x16x32_bf16(qf[m][kf], kfr, s[m][n], 0,0,0);
      }

    if (t == tend-1) {   // only the last tile can touch the diagonal
#pragma unroll
      for (int m=0;m<2;++m)
#pragma unroll
        for (int n=0;n<4;++n)
#pragma unroll
          for (int r=0;r<4;++r) {
            const int qr = q0 + m*16 + lhi*4 + r;
            const int kc = kv0 + n*16 + lr;
            if (kc > qr) s[m][n][r] = -1.0e30f;
          }
    }

    // wave-parallel online softmax (reduce across the 16-lane column groups)
#pragma unroll
    for (int m=0;m<2;++m)
#pragma unroll
      for (int r=0;r<4;++r) {
        float mx = s[m][0][r];
#pragma unroll
        for (int n=1;n<4;++n) mx = fmaxf(mx, s[m][n][r]);
        mx = fmaxf(mx, __shfl_xor(mx, 1));
        mx = fmaxf(mx, __shfl_xor(mx, 2));
        mx = fmaxf(mx, __shfl_xor(mx, 4));
        mx = fmaxf(mx, __shfl_xor(mx, 8));
        const float newm  = fmaxf(rm[m][r], mx);
        const float alpha = __expf(rm[m][r] - newm);
        rm[m][r] = newm;
        float sum = 0.f;
#pragma unroll
        for (int n=0;n<4;++n) {
          const float p = __expf(s[m][n][r] - newm);
          s[m][n][r] = p;
          sum += p;
        }
        sum += __shfl_xor(sum, 1);
        sum += __shfl_xor(sum, 2);
        sum += __shfl_xor(sum, 4);
        sum += __shfl_xor(sum, 8);
        rl[m][r] = rl[m][r]*alpha + sum;
#pragma unroll
        for (int n=0;n<4;++n) o[m][n][r] *= alpha;
      }

    // P -> LDS bf16, XOR-swizzled ([32] rows x 128B would be 32-way conflict)
#pragma unroll
    for (int m=0;m<2;++m)
#pragma unroll
      for (int n=0;n<4;++n)
#pragma unroll
        for (int r=0;r<4;++r) {
          const int row = m*16 + lhi*4 + r;
          const int col = n*16 + lr;
          const int byt = (row*128 + col*2) ^ ((row & 7) << 4);
          *(unsigned short*)((char*)Pw + byt) = f2bf(s[m][n][r]);
        }

    // PV: A = P (swizzled LDS), B = V^T rows (contiguous along kv)
#pragma unroll
    for (int ks=0;ks<2;++ks) {
      bf16x8 pf[2];
#pragma unroll
      for (int m=0;m<2;++m) {
        const int row = m*16 + lr;
        const int byt = (row*128 + ks*64 + lhi*16) ^ ((row & 7) << 4);
        pf[m] = *(const bf16x8*)((char*)Pw + byt);
      }
#pragma unroll
      for (int n=0;n<4;++n) {
        const bf16x8 vf = *(const bf16x8*)&Vh[(size_t)(n*16 + lr)*S_LEN + kv0 + ks*32 + lhi*8];
#pragma unroll
        for (int m=0;m<2;++m)
          o[m][n] = __builtin_amdgcn_mfma_f32_16x16x32_bf16(pf[m], vf, o[m][n], 0,0,0);
      }
    }
  }

#pragma unroll
  for (int m=0;m<2;++m)
#pragma unroll
    for (int r=0;r<4;++r) {
      const float inv = 1.0f / rl[m][r];
      const int qr = q0 + m*16 + lhi*4 + r;
#pragma unroll
      for (int n=0;n<4;++n) {
        const int d = n*16 + lr;
        ctx[(size_t)qr*EMB + h*HD + d] = f2bf(o[m][n][r] * inv);
      }
    }
}

// ---------------- output projection, one batch ----------------
// A = ctx (bf16 [2048][1024], global_load_lds), B = wo (fp32, reg-staged)
__global__ __launch_bounds__(256) void k_oproj(
    const unsigned short* __restrict__ ctx,
    const float* __restrict__ wo,
    const float* __restrict__ bo,
    float* __restrict__ out, int b)
{
  __shared__ unsigned short Al[128*32];
  __shared__ unsigned short Bl[128*32];
  const int tid = threadIdx.x;
  const int m0 = blockIdx.x * 128;
  const int n0 = blockIdx.y * 128;
  const int w = tid >> 6, lane = tid & 63;
  const int wr = w >> 1, wc = w & 1;
  const int lr = lane & 15, lhi = lane >> 4;

  f32x4 acc[4][4];
#pragma unroll
  for (int m=0;m<4;++m)
#pragma unroll
    for (int n=0;n<4;++n) acc[m][n] = (f32x4){0.f,0.f,0.f,0.f};

  for (int k0 = 0; k0 < EMB; k0 += 32) {
    float4 b0[2], b1[2];
#pragma unroll
    for (int j = 0; j < 2; ++j) {
      const int c   = j*256 + tid;
      const int row = c >> 2;
      const int col = (c & 3) << 3;
      const float* bp = wo + (size_t)(n0+row)*EMB + k0 + col;
      b0[j] = *(const float4*)bp;  b1[j] = *(const float4*)(bp+4);
    }
    __syncthreads();
#pragma unroll
    for (int j = 0; j < 2; ++j) {
      const int c   = j*256 + tid;
      const int row = c >> 2;
      const int col = (c & 3) << 3;
      const int ub  = (j*256 + (tid & 192)) * 16;   // wave-uniform LDS byte base
      GLOAD16(ctx + (size_t)(m0+row)*EMB + k0 + col, (char*)Al + ub);
      *(ushort8*)&Bl[row*32 + col] = cvt8(b0[j], b1[j]);
    }
    __syncthreads();
    bf16x8 af[4], bfr[4];
#pragma unroll
    for (int m=0;m<4;++m) af[m]  = *(const bf16x8*)&Al[(wr*64 + m*16 + lr)*32 + lhi*8];
#pragma unroll
    for (int n=0;n<4;++n) bfr[n] = *(const bf16x8*)&Bl[(wc*64 + n*16 + lr)*32 + lhi*8];
#pragma unroll
    for (int m=0;m<4;++m)
#pragma unroll
      for (int n=0;n<4;++n)
        acc[m][n] = __builtin_amdgcn_mfma_f32_16x16x32_bf16(af[m], bfr[n], acc[m][n], 0,0,0);
  }

#pragma unroll
  for (int m=0;m<4;++m)
#pragma unroll
    for (int n=0;n<4;++n)
#pragma unroll
      for (int r=0;r<4;++r) {
        const int i    = m0 + wr*64 + m*16 + lhi*4 + r;
        const int fcol = n0 + wc*64 + n*16 + lr;
        out[((size_t)i*BATCH + b)*EMB + fcol] = acc[m][n][r] + bo[fcol];
      }
}

// ---------------- launch ----------------
extern "C" void kernel_launch(void* const* d_in, const int* in_sizes, int n_in,
                              void* d_out, int out_size, void* d_ws, size_t ws_size,
                              hipStream_t stream) {
  const float* x  = (const float*)d_in[0];
  const float* wq = (const float*)d_in[1];
  const float* bq = (const float*)d_in[2];
  const float* wk = (const float*)d_in[3];
  const float* bk = (const float*)d_in[4];
  const float* wv = (const float*)d_in[5];
  const float* bv = (const float*)d_in[6];
  const float* wo = (const float*)d_in[7];
  const float* bo = (const float*)d_in[8];
  float* out = (float*)d_out;

  char* ws = (char*)d_ws;
  const size_t MB = (size_t)1 << 20;
  const size_t PASS_BYTES = 16*MB;                // Q(4)+K(4)+Vt(4)+ctx(4)
  const bool big = ws_size >= 2*PASS_BYTES;

  unsigned short* Qb[2];  unsigned short* Kb[2];
  unsigned short* Vt[2];  unsigned short* cx[2];
  for (int b = 0; b < 2; ++b) {
    char* base = ws + (big ? (size_t)b*PASS_BYTES : 0);
    Qb[b] = (unsigned short*)(base + 0*MB);
    Kb[b] = (unsigned short*)(base + 4*MB);
    Vt[b] = (unsigned short*)(base + 8*MB);
    cx[b] = (unsigned short*)(base + 12*MB);
  }

  if (big) {
    for (int b = 0; b < 2; ++b)
      k_qkv<<<dim3(16,8,3), 256, 0, stream>>>(x + b*EMB, wq,wk,wv, bq,bk,bv,
                                              Qb[b], Kb[b], Vt[b]);
    for (int b = 0; b < 2; ++b)
      k_attn<<<dim3(16,NH), 256, 0, stream>>>(Qb[b], Kb[b], Vt[b], cx[b]);
    for (int b = 0; b < 2; ++b)
      k_oproj<<<dim3(16,8), 256, 0, stream>>>(cx[b], wo, bo, out, b);
  } else {
    for (int b = 0; b < 2; ++b) {
      k_qkv<<<dim3(16,8,3), 256, 0, stream>>>(x + b*EMB, wq,wk,wv, bq,bk,bv,
                                              Qb[b], Kb[b], Vt[b]);
      k_attn<<<dim3(16,NH), 256, 0, stream>>>(Qb[b], Kb[b], Vt[b], cx[b]);
      k_oproj<<<dim3(16,8), 256, 0, stream>>>(cx[b], wo, bo, out, b);
    }
  }
}

// Round 3
// 340.985 us; speedup vs baseline: 1.0615x; 1.0615x over previous
//
#include <hip/hip_runtime.h>
#include <hip/hip_bf16.h>
#include <stdint.h>

#define S_LEN 2048
#define BATCH 2
#define EMB   1024
#define NH    16
#define HD    64

typedef __bf16 bf16x8 __attribute__((ext_vector_type(8)));
typedef float  f32x4  __attribute__((ext_vector_type(4)));
typedef unsigned short ushort8 __attribute__((ext_vector_type(8)));

__device__ __forceinline__ unsigned short f2bf(float f) {
  unsigned int u = __float_as_uint(f);
  u += 0x7fffu + ((u >> 16) & 1u);
  return (unsigned short)(u >> 16);
}

__device__ __forceinline__ ushort8 cvt8(const float4 a, const float4 b) {
  ushort8 o;
  o[0]=f2bf(a.x); o[1]=f2bf(a.y); o[2]=f2bf(a.z); o[3]=f2bf(a.w);
  o[4]=f2bf(b.x); o[5]=f2bf(b.y); o[6]=f2bf(b.z); o[7]=f2bf(b.w);
  return o;
}

#define GLOAD16(g, l) __builtin_amdgcn_global_load_lds( \
    (const __attribute__((address_space(1))) void*)(g),  \
    (__attribute__((address_space(3))) void*)(l), 16, 0, 0)

// ---------------- QKV projection (fused fp32->bf16 staging) ----------------
// A rows r (stride a_rs f32), token i = r>>ishift, batch-sel = r & ((1<<ishift)-1)
// z=0:Q(scaled+bias) 1:K 2:V(transposed per head)
__global__ __launch_bounds__(256) void k_qkv(
    const float* __restrict__ xA, int a_rs, int ishift,
    const float* __restrict__ wq, const float* __restrict__ wk,
    const float* __restrict__ wv,
    const float* __restrict__ bq, const float* __restrict__ bk,
    const float* __restrict__ bv,
    unsigned short* __restrict__ Qb, unsigned short* __restrict__ Kb,
    unsigned short* __restrict__ Vtb)
{
  __shared__ unsigned short Al[128*32];
  __shared__ unsigned short Bl[128*32];
  const int tid = threadIdx.x;
  const int z  = blockIdx.z;
  const int m0 = blockIdx.x * 128;
  const int n0 = blockIdx.y * 128;
  const int w = tid >> 6, lane = tid & 63;
  const int wr = w >> 1, wc = w & 1;
  const int lr = lane & 15, lhi = lane >> 4;
  const float* wz = (z==0) ? wq : ((z==1) ? wk : wv);

  f32x4 acc[4][4];
#pragma unroll
  for (int m=0;m<4;++m)
#pragma unroll
    for (int n=0;n<4;++n) acc[m][n] = (f32x4){0.f,0.f,0.f,0.f};

  for (int k0 = 0; k0 < EMB; k0 += 32) {
    float4 a0[2], a1[2], b0[2], b1[2];
#pragma unroll
    for (int j = 0; j < 2; ++j) {
      const int c   = j*256 + tid;
      const int row = c >> 2;
      const int col = (c & 3) << 3;
      const float* ap = xA + (size_t)(m0+row)*a_rs + k0 + col;
      const float* bp = wz + (size_t)(n0+row)*EMB + k0 + col;
      a0[j] = *(const float4*)ap;  a1[j] = *(const float4*)(ap+4);
      b0[j] = *(const float4*)bp;  b1[j] = *(const float4*)(bp+4);
    }
    __syncthreads();
#pragma unroll
    for (int j = 0; j < 2; ++j) {
      const int c   = j*256 + tid;
      const int row = c >> 2;
      const int col = (c & 3) << 3;
      *(ushort8*)&Al[row*32 + col] = cvt8(a0[j], a1[j]);
      *(ushort8*)&Bl[row*32 + col] = cvt8(b0[j], b1[j]);
    }
    __syncthreads();
    bf16x8 af[4], bfr[4];
#pragma unroll
    for (int m=0;m<4;++m) af[m]  = *(const bf16x8*)&Al[(wr*64 + m*16 + lr)*32 + lhi*8];
#pragma unroll
    for (int n=0;n<4;++n) bfr[n] = *(const bf16x8*)&Bl[(wc*64 + n*16 + lr)*32 + lhi*8];
#pragma unroll
    for (int m=0;m<4;++m)
#pragma unroll
      for (int n=0;n<4;++n)
        acc[m][n] = __builtin_amdgcn_mfma_f32_16x16x32_bf16(af[m], bfr[n], acc[m][n], 0,0,0);
  }

  const float scale = (z==0) ? 0.125f : 1.0f;   // D^-0.5
  const float* bias = (z==0) ? bq : ((z==1) ? bk : bv);
  const int bmask = (1 << ishift) - 1;
#pragma unroll
  for (int m=0;m<4;++m)
#pragma unroll
    for (int n=0;n<4;++n)
#pragma unroll
      for (int r=0;r<4;++r) {
        const int rr   = m0 + wr*64 + m*16 + lhi*4 + r;   // A row
        const int fcol = n0 + wc*64 + n*16 + lr;          // f = h*64+d
        const float v = (acc[m][n][r] + bias[fcol]) * scale;
        const unsigned short ov = f2bf(v);
        const int i = rr >> ishift, bsel = rr & bmask;
        const int h = fcol >> 6, d = fcol & 63;
        const int hh = bsel*NH + h;
        if (z == 0)      Qb [((size_t)hh*S_LEN + i)*HD + d] = ov;
        else if (z == 1) Kb [((size_t)hh*S_LEN + i)*HD + d] = ov;
        else             Vtb[((size_t)hh*HD + d)*S_LEN + i] = ov;
      }
}

// ---------------- causal flash attention ----------------
// grid (S/64, nbh), 4 waves/block, each wave owns 16 q-rows independently
__global__ __launch_bounds__(256,4) void k_attn(
    const unsigned short* __restrict__ Q,
    const unsigned short* __restrict__ K,
    const unsigned short* __restrict__ Vt,
    unsigned short* __restrict__ ctx, int bshift)
{
  __shared__ unsigned short Pl[4*1024];
  const int tid = threadIdx.x;
  const int w = tid >> 6, lane = tid & 63;
  const int lr = lane & 15, lhi = lane >> 4;
  const int hh = blockIdx.y;
  const int h  = hh & (NH-1);
  const int badd = hh >> 4;            // 0 in per-batch mode (grid.y = 16)
  const int q0 = blockIdx.x*64 + w*16;
  const unsigned short* Qh = Q  + (size_t)hh*S_LEN*HD;
  const unsigned short* Kh = K  + (size_t)hh*S_LEN*HD;
  const unsigned short* Vh = Vt + (size_t)hh*HD*S_LEN;
  unsigned short* Pw = Pl + w*1024;

  bf16x8 qf[2];
#pragma unroll
  for (int kf=0;kf<2;++kf)
    qf[kf] = *(const bf16x8*)&Qh[(size_t)(q0 + lr)*HD + kf*32 + lhi*8];

  f32x4 o[4];
  float rm[4], rl[4];
#pragma unroll
  for (int n=0;n<4;++n) o[n] = (f32x4){0.f,0.f,0.f,0.f};
#pragma unroll
  for (int r=0;r<4;++r) { rm[r] = -3.0e38f; rl[r] = 0.f; }

  const int tend = (q0 >> 6) + 1;
  for (int t = 0; t < tend; ++t) {
    const int kv0 = t*64;
    f32x4 s[4];
#pragma unroll
    for (int n=0;n<4;++n) s[n] = (f32x4){0.f,0.f,0.f,0.f};

#pragma unroll
    for (int n=0;n<4;++n)
#pragma unroll
      for (int kf=0;kf<2;++kf) {
        const bf16x8 kfr = *(const bf16x8*)&Kh[(size_t)(kv0 + n*16 + lr)*HD + kf*32 + lhi*8];
        s[n] = __builtin_amdgcn_mfma_f32_16x16x32_bf16(qf[kf], kfr, s[n], 0,0,0);
      }

    if (t == tend-1) {   // only the last tile touches the diagonal
#pragma unroll
      for (int n=0;n<4;++n)
#pragma unroll
        for (int r=0;r<4;++r) {
          const int qr = q0 + lhi*4 + r;
          const int kc = kv0 + n*16 + lr;
          if (kc > qr) s[n][r] = -1.0e30f;
        }
    }

    // wave-parallel online softmax (reduce across 16-lane column groups)
#pragma unroll
    for (int r=0;r<4;++r) {
      float mx = fmaxf(fmaxf(s[0][r], s[1][r]), fmaxf(s[2][r], s[3][r]));
      mx = fmaxf(mx, __shfl_xor(mx, 1));
      mx = fmaxf(mx, __shfl_xor(mx, 2));
      mx = fmaxf(mx, __shfl_xor(mx, 4));
      mx = fmaxf(mx, __shfl_xor(mx, 8));
      const float newm  = fmaxf(rm[r], mx);
      const float alpha = __expf(rm[r] - newm);
      rm[r] = newm;
      float sum = 0.f;
#pragma unroll
      for (int n=0;n<4;++n) {
        const float p = __expf(s[n][r] - newm);
        s[n][r] = p;
        sum += p;
      }
      sum += __shfl_xor(sum, 1);
      sum += __shfl_xor(sum, 2);
      sum += __shfl_xor(sum, 4);
      sum += __shfl_xor(sum, 8);
      rl[r] = rl[r]*alpha + sum;
#pragma unroll
      for (int n=0;n<4;++n) o[n][r] *= alpha;
    }

    // P -> LDS bf16, XOR-swizzled (16 rows x 128B stride)
#pragma unroll
    for (int n=0;n<4;++n)
#pragma unroll
      for (int r=0;r<4;++r) {
        const int row = lhi*4 + r;
        const int col = n*16 + lr;
        const int byt = (row*128 + col*2) ^ ((row & 7) << 4);
        *(unsigned short*)((char*)Pw + byt) = f2bf(s[n][r]);
      }

    // PV: A = P (swizzled LDS), B = V^T rows (contiguous along kv)
#pragma unroll
    for (int ks=0;ks<2;++ks) {
      const int byt = (lr*128 + ks*64 + lhi*16) ^ ((lr & 7) << 4);
      const bf16x8 pf = *(const bf16x8*)((char*)Pw + byt);
#pragma unroll
      for (int n=0;n<4;++n) {
        const bf16x8 vf = *(const bf16x8*)&Vh[(size_t)(n*16 + lr)*S_LEN + kv0 + ks*32 + lhi*8];
        o[n] = __builtin_amdgcn_mfma_f32_16x16x32_bf16(pf, vf, o[n], 0,0,0);
      }
    }
  }

#pragma unroll
  for (int r=0;r<4;++r) {
    const float inv = 1.0f / rl[r];
    const int qr = q0 + lhi*4 + r;
    const size_t trow = ((size_t)qr << bshift) + badd;
#pragma unroll
    for (int n=0;n<4;++n) {
      const int d = n*16 + lr;
      ctx[trow*EMB + h*HD + d] = f2bf(o[n][r] * inv);
    }
  }
}

// ---------------- output projection ----------------
// A = ctx (bf16, rows r stride EMB, global_load_lds), B = wo (fp32, reg-staged)
// out row = r * orm (caller pre-offsets out base for per-batch mode)
__global__ __launch_bounds__(256) void k_oproj(
    const unsigned short* __restrict__ ctxA,
    const float* __restrict__ wo,
    const float* __restrict__ bo,
    float* __restrict__ outb, int orm)
{
  __shared__ unsigned short Al[128*32];
  __shared__ unsigned short Bl[128*32];
  const int tid = threadIdx.x;
  const int m0 = blockIdx.x * 128;
  const int n0 = blockIdx.y * 128;
  const int w = tid >> 6, lane = tid & 63;
  const int wr = w >> 1, wc = w & 1;
  const int lr = lane & 15, lhi = lane >> 4;

  f32x4 acc[4][4];
#pragma unroll
  for (int m=0;m<4;++m)
#pragma unroll
    for (int n=0;n<4;++n) acc[m][n] = (f32x4){0.f,0.f,0.f,0.f};

  for (int k0 = 0; k0 < EMB; k0 += 32) {
    float4 b0[2], b1[2];
#pragma unroll
    for (int j = 0; j < 2; ++j) {
      const int c   = j*256 + tid;
      const int row = c >> 2;
      const int col = (c & 3) << 3;
      const float* bp = wo + (size_t)(n0+row)*EMB + k0 + col;
      b0[j] = *(const float4*)bp;  b1[j] = *(const float4*)(bp+4);
    }
    __syncthreads();
#pragma unroll
    for (int j = 0; j < 2; ++j) {
      const int c   = j*256 + tid;
      const int row = c >> 2;
      const int col = (c & 3) << 3;
      const int ub  = (j*256 + (tid & 192)) * 16;   // wave-uniform LDS byte base
      GLOAD16(ctxA + (size_t)(m0+row)*EMB + k0 + col, (char*)Al + ub);
      *(ushort8*)&Bl[row*32 + col] = cvt8(b0[j], b1[j]);
    }
    __syncthreads();
    bf16x8 af[4], bfr[4];
#pragma unroll
    for (int m=0;m<4;++m) af[m]  = *(const bf16x8*)&Al[(wr*64 + m*16 + lr)*32 + lhi*8];
#pragma unroll
    for (int n=0;n<4;++n) bfr[n] = *(const bf16x8*)&Bl[(wc*64 + n*16 + lr)*32 + lhi*8];
#pragma unroll
    for (int m=0;m<4;++m)
#pragma unroll
      for (int n=0;n<4;++n)
        acc[m][n] = __builtin_amdgcn_mfma_f32_16x16x32_bf16(af[m], bfr[n], acc[m][n], 0,0,0);
  }

#pragma unroll
  for (int m=0;m<4;++m)
#pragma unroll
    for (int n=0;n<4;++n)
#pragma unroll
      for (int r=0;r<4;++r) {
        const int rr   = m0 + wr*64 + m*16 + lhi*4 + r;
        const int fcol = n0 + wc*64 + n*16 + lr;
        outb[(size_t)rr*orm*EMB + fcol] = acc[m][n][r] + bo[fcol];
      }
}

// ---------------- launch ----------------
extern "C" void kernel_launch(void* const* d_in, const int* in_sizes, int n_in,
                              void* d_out, int out_size, void* d_ws, size_t ws_size,
                              hipStream_t stream) {
  const float* x  = (const float*)d_in[0];
  const float* wq = (const float*)d_in[1];
  const float* bq = (const float*)d_in[2];
  const float* wk = (const float*)d_in[3];
  const float* bk = (const float*)d_in[4];
  const float* wv = (const float*)d_in[5];
  const float* bv = (const float*)d_in[6];
  const float* wo = (const float*)d_in[7];
  const float* bo = (const float*)d_in[8];
  float* out = (float*)d_out;

  char* ws = (char*)d_ws;
  const size_t MB = (size_t)1 << 20;

  if (ws_size >= 32*MB) {
    // merged path: one dispatch per stage, both batches (32 head-buffers)
    unsigned short* Q  = (unsigned short*)(ws + 0*MB);
    unsigned short* K  = (unsigned short*)(ws + 8*MB);
    unsigned short* Vt = (unsigned short*)(ws + 16*MB);
    unsigned short* cx = (unsigned short*)(ws + 24*MB);
    k_qkv<<<dim3(32,8,3), 256, 0, stream>>>(x, EMB, 1, wq,wk,wv, bq,bk,bv, Q,K,Vt);
    k_attn<<<dim3(32,32), 256, 0, stream>>>(Q, K, Vt, cx, 1);
    k_oproj<<<dim3(32,8), 256, 0, stream>>>(cx, wo, bo, out, 1);
  } else {
    // small-ws fallback: per-batch pipeline reusing one 16 MB block
    unsigned short* Q  = (unsigned short*)(ws + 0*MB);
    unsigned short* K  = (unsigned short*)(ws + 4*MB);
    unsigned short* Vt = (unsigned short*)(ws + 8*MB);
    unsigned short* cx = (unsigned short*)(ws + 12*MB);
    for (int b = 0; b < 2; ++b) {
      k_qkv<<<dim3(16,8,3), 256, 0, stream>>>(x + b*EMB, 2*EMB, 0,
                                              wq,wk,wv, bq,bk,bv, Q,K,Vt);
      k_attn<<<dim3(32,16), 256, 0, stream>>>(Q, K, Vt, cx, 0);
      k_oproj<<<dim3(16,8), 256, 0, stream>>>(cx, wo, bo, out + b*EMB, 2);
    }
  }
}

// Round 4
// 228.172 us; speedup vs baseline: 1.5864x; 1.4944x over previous
//
#include <hip/hip_runtime.h>
#include <hip/hip_bf16.h>
#include <stdint.h>

#define S_LEN 2048
#define BATCH 2
#define EMB   1024
#define NH    16
#define HD    64

typedef __bf16 bf16x8 __attribute__((ext_vector_type(8)));
typedef float  f32x4  __attribute__((ext_vector_type(4)));
typedef unsigned short ushort8 __attribute__((ext_vector_type(8)));

__device__ __forceinline__ unsigned short f2bf(float f) {
  unsigned int u = __float_as_uint(f);
  u += 0x7fffu + ((u >> 16) & 1u);
  return (unsigned short)(u >> 16);
}

__device__ __forceinline__ ushort8 cvt8(const float4 a, const float4 b) {
  ushort8 o;
  o[0]=f2bf(a.x); o[1]=f2bf(a.y); o[2]=f2bf(a.z); o[3]=f2bf(a.w);
  o[4]=f2bf(b.x); o[5]=f2bf(b.y); o[6]=f2bf(b.z); o[7]=f2bf(b.w);
  return o;
}

#define GLOAD16(g, l) __builtin_amdgcn_global_load_lds( \
    (const __attribute__((address_space(1))) void*)(g),  \
    (__attribute__((address_space(3))) void*)(l), 16, 0, 0)

// ---------------- QKV projection (fused fp32->bf16 staging) ----------------
__global__ __launch_bounds__(256) void k_qkv(
    const float* __restrict__ xA, int a_rs, int ishift,
    const float* __restrict__ wq, const float* __restrict__ wk,
    const float* __restrict__ wv,
    const float* __restrict__ bq, const float* __restrict__ bk,
    const float* __restrict__ bv,
    unsigned short* __restrict__ Qb, unsigned short* __restrict__ Kb,
    unsigned short* __restrict__ Vtb)
{
  __shared__ unsigned short Al[128*32];
  __shared__ unsigned short Bl[128*32];
  const int tid = threadIdx.x;
  const int z  = blockIdx.z;
  const int m0 = blockIdx.x * 128;
  const int n0 = blockIdx.y * 128;
  const int w = tid >> 6, lane = tid & 63;
  const int wr = w >> 1, wc = w & 1;
  const int lr = lane & 15, lhi = lane >> 4;
  const float* wz = (z==0) ? wq : ((z==1) ? wk : wv);

  f32x4 acc[4][4];
#pragma unroll
  for (int m=0;m<4;++m)
#pragma unroll
    for (int n=0;n<4;++n) acc[m][n] = (f32x4){0.f,0.f,0.f,0.f};

  for (int k0 = 0; k0 < EMB; k0 += 32) {
    float4 a0[2], a1[2], b0[2], b1[2];
#pragma unroll
    for (int j = 0; j < 2; ++j) {
      const int c   = j*256 + tid;
      const int row = c >> 2;
      const int col = (c & 3) << 3;
      const float* ap = xA + (size_t)(m0+row)*a_rs + k0 + col;
      const float* bp = wz + (size_t)(n0+row)*EMB + k0 + col;
      a0[j] = *(const float4*)ap;  a1[j] = *(const float4*)(ap+4);
      b0[j] = *(const float4*)bp;  b1[j] = *(const float4*)(bp+4);
    }
    __syncthreads();
#pragma unroll
    for (int j = 0; j < 2; ++j) {
      const int c   = j*256 + tid;
      const int row = c >> 2;
      const int col = (c & 3) << 3;
      *(ushort8*)&Al[row*32 + col] = cvt8(a0[j], a1[j]);
      *(ushort8*)&Bl[row*32 + col] = cvt8(b0[j], b1[j]);
    }
    __syncthreads();
    bf16x8 af[4], bfr[4];
#pragma unroll
    for (int m=0;m<4;++m) af[m]  = *(const bf16x8*)&Al[(wr*64 + m*16 + lr)*32 + lhi*8];
#pragma unroll
    for (int n=0;n<4;++n) bfr[n] = *(const bf16x8*)&Bl[(wc*64 + n*16 + lr)*32 + lhi*8];
#pragma unroll
    for (int m=0;m<4;++m)
#pragma unroll
      for (int n=0;n<4;++n)
        acc[m][n] = __builtin_amdgcn_mfma_f32_16x16x32_bf16(af[m], bfr[n], acc[m][n], 0,0,0);
  }

  const float scale = (z==0) ? 0.125f : 1.0f;   // D^-0.5
  const float* bias = (z==0) ? bq : ((z==1) ? bk : bv);
  const int bmask = (1 << ishift) - 1;
#pragma unroll
  for (int m=0;m<4;++m)
#pragma unroll
    for (int n=0;n<4;++n)
#pragma unroll
      for (int r=0;r<4;++r) {
        const int rr   = m0 + wr*64 + m*16 + lhi*4 + r;
        const int fcol = n0 + wc*64 + n*16 + lr;
        const float v = (acc[m][n][r] + bias[fcol]) * scale;
        const unsigned short ov = f2bf(v);
        const int i = rr >> ishift, bsel = rr & bmask;
        const int h = fcol >> 6, d = fcol & 63;
        const int hh = bsel*NH + h;
        if (z == 0)      Qb [((size_t)hh*S_LEN + i)*HD + d] = ov;
        else if (z == 1) Kb [((size_t)hh*S_LEN + i)*HD + d] = ov;
        else             Vtb[((size_t)hh*HD + d)*S_LEN + i] = ov;
      }
}

// ---------------- causal flash attention (block-coop LDS-staged) ----------
// 1D grid of nhh*16 blocks. lin -> (hh, chunk) with complementary chunk
// pairing so co-resident blocks have constant total work and share a head.
// Block = 4 waves x 32 q-rows = 128 q-rows; K/V 64-tiles double-buffered in
// LDS via global_load_lds with counted vmcnt(4) (never drained in-loop).
__global__ __launch_bounds__(256,2) void k_attn(
    const unsigned short* __restrict__ Q,
    const unsigned short* __restrict__ K,
    const unsigned short* __restrict__ Vt,
    unsigned short* __restrict__ ctx, int bshift, int hsh)
{
  __shared__ unsigned short KL[2][64*64];   // 8 KB each, XOR-swizzled rows
  __shared__ unsigned short VL[2][64*64];
  __shared__ unsigned short Pl[4][2048];    // per-wave P, XOR-swizzled

  const int tid = threadIdx.x;
  const int w = tid >> 6, lane = tid & 63;
  const int lr = lane & 15, lhi = lane >> 4;

  const int lin = blockIdx.x;
  const int cc  = lin >> hsh;
  const int chunk = (cc < 8) ? cc : (23 - cc);
  const int hh  = lin & ((1 << hsh) - 1);
  const int q0  = chunk*128 + w*32;

  const unsigned short* Qh = Q  + (size_t)hh*S_LEN*HD;
  const unsigned short* Kh = K  + (size_t)hh*S_LEN*HD;
  const unsigned short* Vh = Vt + (size_t)hh*HD*S_LEN;
  unsigned short* Pw = Pl[w];

  // Q fragments (32 rows x 64)
  bf16x8 qf[2][2];
#pragma unroll
  for (int m=0;m<2;++m)
#pragma unroll
    for (int kf=0;kf<2;++kf)
      qf[m][kf] = *(const bf16x8*)&Qh[(size_t)(q0 + m*16 + lr)*HD + kf*32 + lhi*8];

  f32x4 o[2][4];
  float rm[2][4], rl[2][4];
#pragma unroll
  for (int m=0;m<2;++m) {
#pragma unroll
    for (int n=0;n<4;++n) o[m][n] = (f32x4){0.f,0.f,0.f,0.f};
#pragma unroll
    for (int r=0;r<4;++r) { rm[m][r] = -3.0e38f; rl[m][r] = 0.f; }
  }

  const int wtend = ((q0 + 31) >> 6) + 1;   // tiles this wave computes
  const int tmax  = 2*chunk + 2;            // tiles the block stages

  // stage K/V tile tt into buffer bb2: LDS linear dest, inverse-swizzled
  // global source (rule 21: swizzle both-sides-or-neither with gload_lds)
  auto STAGE = [&](int tt, int bb2) {
    const int kv0 = tt*64;
#pragma unroll
    for (int j = 0; j < 2; ++j) {
      const int c   = j*256 + tid;
      const int row = c >> 3;                       // dest row (0..63)
      const int sb  = (c*16) ^ ((row & 7) << 4);    // source byte in tile
      const int el  = (sb & 127) >> 1;              // element within row
      const int ub  = (j*256 + (tid & 192)) * 16;   // wave-uniform LDS base
      GLOAD16(Kh + (size_t)(kv0+row)*HD + el,        (char*)KL[bb2] + ub);
      GLOAD16(Vh + (size_t)row*S_LEN + kv0 + el,     (char*)VL[bb2] + ub);
    }
  };

  STAGE(0, 0);
  int bb = 0;
  for (int t = 0; t < tmax; ++t) {
    if (t + 1 < tmax) {
      STAGE(t+1, bb^1);
      asm volatile("s_waitcnt vmcnt(4)" ::: "memory");   // cur tile ready
    } else {
      asm volatile("s_waitcnt vmcnt(0)" ::: "memory");
    }
    __builtin_amdgcn_s_barrier();

    if (t < wtend) {
      const int kv0 = t*64;
      const char* KB = (const char*)KL[bb];
      const char* VB = (const char*)VL[bb];

      f32x4 s[2][4];
#pragma unroll
      for (int m=0;m<2;++m)
#pragma unroll
        for (int n=0;n<4;++n) s[m][n] = (f32x4){0.f,0.f,0.f,0.f};

#pragma unroll
      for (int n=0;n<4;++n)
#pragma unroll
        for (int kf=0;kf<2;++kf) {
          const int row = n*16 + lr;
          const int byt = ((row<<7) + kf*64 + lhi*16) ^ ((row & 7) << 4);
          const bf16x8 kfr = *(const bf16x8*)(KB + byt);
#pragma unroll
          for (int m=0;m<2;++m)
            s[m][n] = __builtin_amdgcn_mfma_f32_16x16x32_bf16(qf[m][kf], kfr, s[m][n], 0,0,0);
        }

      if (t == wtend-1) {   // only the last tile touches the diagonal
#pragma unroll
        for (int m=0;m<2;++m)
#pragma unroll
          for (int n=0;n<4;++n)
#pragma unroll
            for (int r=0;r<4;++r) {
              const int qr = q0 + m*16 + lhi*4 + r;
              const int kc = kv0 + n*16 + lr;
              if (kc > qr) s[m][n][r] = -1.0e30f;
            }
      }

      // wave-parallel online softmax (reduce across 16-lane column groups)
#pragma unroll
      for (int m=0;m<2;++m)
#pragma unroll
        for (int r=0;r<4;++r) {
          float mx = fmaxf(fmaxf(s[m][0][r], s[m][1][r]),
                           fmaxf(s[m][2][r], s[m][3][r]));
          mx = fmaxf(mx, __shfl_xor(mx, 1));
          mx = fmaxf(mx, __shfl_xor(mx, 2));
          mx = fmaxf(mx, __shfl_xor(mx, 4));
          mx = fmaxf(mx, __shfl_xor(mx, 8));
          const float newm  = fmaxf(rm[m][r], mx);
          const float alpha = __expf(rm[m][r] - newm);
          rm[m][r] = newm;
          float sum = 0.f;
#pragma unroll
          for (int n=0;n<4;++n) {
            const float p = __expf(s[m][n][r] - newm);
            s[m][n][r] = p;
            sum += p;
          }
          sum += __shfl_xor(sum, 1);
          sum += __shfl_xor(sum, 2);
          sum += __shfl_xor(sum, 4);
          sum += __shfl_xor(sum, 8);
          rl[m][r] = rl[m][r]*alpha + sum;
#pragma unroll
          for (int n=0;n<4;++n) o[m][n][r] *= alpha;
        }

      // P -> LDS bf16, XOR-swizzled
#pragma unroll
      for (int m=0;m<2;++m)
#pragma unroll
        for (int n=0;n<4;++n)
#pragma unroll
          for (int r=0;r<4;++r) {
            const int row = m*16 + lhi*4 + r;
            const int col = n*16 + lr;
            const int byt = (row*128 + col*2) ^ ((row & 7) << 4);
            *(unsigned short*)((char*)Pw + byt) = f2bf(s[m][n][r]);
          }

      // PV: A = P (swizzled LDS), B = V^T rows from staged tile
#pragma unroll
      for (int ks=0;ks<2;++ks) {
        bf16x8 pf[2];
#pragma unroll
        for (int m=0;m<2;++m) {
          const int row = m*16 + lr;
          const int byt = (row*128 + ks*64 + lhi*16) ^ ((row & 7) << 4);
          pf[m] = *(const bf16x8*)((char*)Pw + byt);
        }
#pragma unroll
        for (int n=0;n<4;++n) {
          const int row = n*16 + lr;
          const int byt = ((row<<7) + ks*64 + lhi*16) ^ ((row & 7) << 4);
          const bf16x8 vf = *(const bf16x8*)(VB + byt);
#pragma unroll
          for (int m=0;m<2;++m)
            o[m][n] = __builtin_amdgcn_mfma_f32_16x16x32_bf16(pf[m], vf, o[m][n], 0,0,0);
        }
      }
    }
    __builtin_amdgcn_s_barrier();
    bb ^= 1;
  }

  const int h = hh & (NH-1);
  const int badd = hh >> 4;
#pragma unroll
  for (int m=0;m<2;++m)
#pragma unroll
    for (int r=0;r<4;++r) {
      const float inv = 1.0f / rl[m][r];
      const int qr = q0 + m*16 + lhi*4 + r;
      const size_t trow = ((size_t)qr << bshift) + badd;
#pragma unroll
      for (int n=0;n<4;++n) {
        const int d = n*16 + lr;
        ctx[trow*EMB + h*HD + d] = f2bf(o[m][n][r] * inv);
      }
    }
}

// ---------------- output projection ----------------
__global__ __launch_bounds__(256) void k_oproj(
    const unsigned short* __restrict__ ctxA,
    const float* __restrict__ wo,
    const float* __restrict__ bo,
    float* __restrict__ outb, int orm)
{
  __shared__ unsigned short Al[128*32];
  __shared__ unsigned short Bl[128*32];
  const int tid = threadIdx.x;
  const int m0 = blockIdx.x * 128;
  const int n0 = blockIdx.y * 128;
  const int w = tid >> 6, lane = tid & 63;
  const int wr = w >> 1, wc = w & 1;
  const int lr = lane & 15, lhi = lane >> 4;

  f32x4 acc[4][4];
#pragma unroll
  for (int m=0;m<4;++m)
#pragma unroll
    for (int n=0;n<4;++n) acc[m][n] = (f32x4){0.f,0.f,0.f,0.f};

  for (int k0 = 0; k0 < EMB; k0 += 32) {
    float4 b0[2], b1[2];
#pragma unroll
    for (int j = 0; j < 2; ++j) {
      const int c   = j*256 + tid;
      const int row = c >> 2;
      const int col = (c & 3) << 3;
      const float* bp = wo + (size_t)(n0+row)*EMB + k0 + col;
      b0[j] = *(const float4*)bp;  b1[j] = *(const float4*)(bp+4);
    }
    __syncthreads();
#pragma unroll
    for (int j = 0; j < 2; ++j) {
      const int c   = j*256 + tid;
      const int row = c >> 2;
      const int col = (c & 3) << 3;
      const int ub  = (j*256 + (tid & 192)) * 16;
      GLOAD16(ctxA + (size_t)(m0+row)*EMB + k0 + col, (char*)Al + ub);
      *(ushort8*)&Bl[row*32 + col] = cvt8(b0[j], b1[j]);
    }
    __syncthreads();
    bf16x8 af[4], bfr[4];
#pragma unroll
    for (int m=0;m<4;++m) af[m]  = *(const bf16x8*)&Al[(wr*64 + m*16 + lr)*32 + lhi*8];
#pragma unroll
    for (int n=0;n<4;++n) bfr[n] = *(const bf16x8*)&Bl[(wc*64 + n*16 + lr)*32 + lhi*8];
#pragma unroll
    for (int m=0;m<4;++m)
#pragma unroll
      for (int n=0;n<4;++n)
        acc[m][n] = __builtin_amdgcn_mfma_f32_16x16x32_bf16(af[m], bfr[n], acc[m][n], 0,0,0);
  }

#pragma unroll
  for (int m=0;m<4;++m)
#pragma unroll
    for (int n=0;n<4;++n)
#pragma unroll
      for (int r=0;r<4;++r) {
        const int rr   = m0 + wr*64 + m*16 + lhi*4 + r;
        const int fcol = n0 + wc*64 + n*16 + lr;
        outb[(size_t)rr*orm*EMB + fcol] = acc[m][n][r] + bo[fcol];
      }
}

// ---------------- launch ----------------
extern "C" void kernel_launch(void* const* d_in, const int* in_sizes, int n_in,
                              void* d_out, int out_size, void* d_ws, size_t ws_size,
                              hipStream_t stream) {
  const float* x  = (const float*)d_in[0];
  const float* wq = (const float*)d_in[1];
  const float* bq = (const float*)d_in[2];
  const float* wk = (const float*)d_in[3];
  const float* bk = (const float*)d_in[4];
  const float* wv = (const float*)d_in[5];
  const float* bv = (const float*)d_in[6];
  const float* wo = (const float*)d_in[7];
  const float* bo = (const float*)d_in[8];
  float* out = (float*)d_out;

  char* ws = (char*)d_ws;
  const size_t MB = (size_t)1 << 20;

  if (ws_size >= 32*MB) {
    unsigned short* Q  = (unsigned short*)(ws + 0*MB);
    unsigned short* K  = (unsigned short*)(ws + 8*MB);
    unsigned short* Vt = (unsigned short*)(ws + 16*MB);
    unsigned short* cx = (unsigned short*)(ws + 24*MB);
    k_qkv<<<dim3(32,8,3), 256, 0, stream>>>(x, EMB, 1, wq,wk,wv, bq,bk,bv, Q,K,Vt);
    k_attn<<<512, 256, 0, stream>>>(Q, K, Vt, cx, 1, 5);
    k_oproj<<<dim3(32,8), 256, 0, stream>>>(cx, wo, bo, out, 1);
  } else {
    unsigned short* Q  = (unsigned short*)(ws + 0*MB);
    unsigned short* K  = (unsigned short*)(ws + 4*MB);
    unsigned short* Vt = (unsigned short*)(ws + 8*MB);
    unsigned short* cx = (unsigned short*)(ws + 12*MB);
    for (int b = 0; b < 2; ++b) {
      k_qkv<<<dim3(16,8,3), 256, 0, stream>>>(x + b*EMB, 2*EMB, 0,
                                              wq,wk,wv, bq,bk,bv, Q,K,Vt);
      k_attn<<<256, 256, 0, stream>>>(Q, K, Vt, cx, 0, 4);
      k_oproj<<<dim3(16,8), 256, 0, stream>>>(cx, wo, bo, out + b*EMB, 2);
    }
  }
}

// Round 5
// 175.198 us; speedup vs baseline: 2.0661x; 1.3024x over previous
//
#include <hip/hip_runtime.h>
#include <hip/hip_bf16.h>
#include <stdint.h>

#define S_LEN 2048
#define BATCH 2
#define EMB   1024
#define NH    16
#define HD    64

typedef __bf16 bf16x8 __attribute__((ext_vector_type(8)));
typedef float  f32x4  __attribute__((ext_vector_type(4)));
typedef unsigned short ushort8 __attribute__((ext_vector_type(8)));

__device__ __forceinline__ unsigned short f2bf(float f) {
  unsigned int u = __float_as_uint(f);
  u += 0x7fffu + ((u >> 16) & 1u);
  return (unsigned short)(u >> 16);
}

__device__ __forceinline__ ushort8 cvt8(const float4 a, const float4 b) {
  ushort8 o;
  o[0]=f2bf(a.x); o[1]=f2bf(a.y); o[2]=f2bf(a.z); o[3]=f2bf(a.w);
  o[4]=f2bf(b.x); o[5]=f2bf(b.y); o[6]=f2bf(b.z); o[7]=f2bf(b.w);
  return o;
}

#define GLOAD16(g, l) __builtin_amdgcn_global_load_lds( \
    (const __attribute__((address_space(1))) void*)(g),  \
    (__attribute__((address_space(3))) void*)(l), 16, 0, 0)

// ---------------- QKV projection (fused fp32->bf16 staging) ----------------
__global__ __launch_bounds__(256) void k_qkv(
    const float* __restrict__ xA, int a_rs, int ishift,
    const float* __restrict__ wq, const float* __restrict__ wk,
    const float* __restrict__ wv,
    const float* __restrict__ bq, const float* __restrict__ bk,
    const float* __restrict__ bv,
    unsigned short* __restrict__ Qb, unsigned short* __restrict__ Kb,
    unsigned short* __restrict__ Vtb)
{
  __shared__ unsigned short Al[128*32];
  __shared__ unsigned short Bl[128*32];
  const int tid = threadIdx.x;
  const int z  = blockIdx.z;
  const int m0 = blockIdx.x * 128;
  const int n0 = blockIdx.y * 128;
  const int w = tid >> 6, lane = tid & 63;
  const int wr = w >> 1, wc = w & 1;
  const int lr = lane & 15, lhi = lane >> 4;
  const float* wz = (z==0) ? wq : ((z==1) ? wk : wv);

  f32x4 acc[4][4];
#pragma unroll
  for (int m=0;m<4;++m)
#pragma unroll
    for (int n=0;n<4;++n) acc[m][n] = (f32x4){0.f,0.f,0.f,0.f};

  for (int k0 = 0; k0 < EMB; k0 += 32) {
    float4 a0[2], a1[2], b0[2], b1[2];
#pragma unroll
    for (int j = 0; j < 2; ++j) {
      const int c   = j*256 + tid;
      const int row = c >> 2;
      const int col = (c & 3) << 3;
      const float* ap = xA + (size_t)(m0+row)*a_rs + k0 + col;
      const float* bp = wz + (size_t)(n0+row)*EMB + k0 + col;
      a0[j] = *(const float4*)ap;  a1[j] = *(const float4*)(ap+4);
      b0[j] = *(const float4*)bp;  b1[j] = *(const float4*)(bp+4);
    }
    __syncthreads();
#pragma unroll
    for (int j = 0; j < 2; ++j) {
      const int c   = j*256 + tid;
      const int row = c >> 2;
      const int col = (c & 3) << 3;
      *(ushort8*)&Al[row*32 + col] = cvt8(a0[j], a1[j]);
      *(ushort8*)&Bl[row*32 + col] = cvt8(b0[j], b1[j]);
    }
    __syncthreads();
    bf16x8 af[4], bfr[4];
#pragma unroll
    for (int m=0;m<4;++m) af[m]  = *(const bf16x8*)&Al[(wr*64 + m*16 + lr)*32 + lhi*8];
#pragma unroll
    for (int n=0;n<4;++n) bfr[n] = *(const bf16x8*)&Bl[(wc*64 + n*16 + lr)*32 + lhi*8];
#pragma unroll
    for (int m=0;m<4;++m)
#pragma unroll
      for (int n=0;n<4;++n)
        acc[m][n] = __builtin_amdgcn_mfma_f32_16x16x32_bf16(af[m], bfr[n], acc[m][n], 0,0,0);
  }

  const float scale = (z==0) ? 0.125f : 1.0f;   // D^-0.5
  const float* bias = (z==0) ? bq : ((z==1) ? bk : bv);
  const int bmask = (1 << ishift) - 1;
#pragma unroll
  for (int m=0;m<4;++m)
#pragma unroll
    for (int n=0;n<4;++n)
#pragma unroll
      for (int r=0;r<4;++r) {
        const int rr   = m0 + wr*64 + m*16 + lhi*4 + r;
        const int fcol = n0 + wc*64 + n*16 + lr;
        const float v = (acc[m][n][r] + bias[fcol]) * scale;
        const unsigned short ov = f2bf(v);
        const int i = rr >> ishift, bsel = rr & bmask;
        const int h = fcol >> 6, d = fcol & 63;
        const int hh = bsel*NH + h;
        if (z == 0)      Qb [((size_t)hh*S_LEN + i)*HD + d] = ov;
        else if (z == 1) Kb [((size_t)hh*S_LEN + i)*HD + d] = ov;
        else             Vtb[((size_t)hh*HD + d)*S_LEN + i] = ov;
      }
}

// ---------------- causal flash attention (swapped-QK^T, LDS-staged) -------
// S^T = MFMA(A=K, B=Q): lane holds 16 S-values of q-col (lane&15) -> softmax
// is in-register + 2 shfl. PV as O^T = MFMA(A=V^T, B=P). K/V 64-tiles
// double-buffered in LDS via global_load_lds, counted vmcnt(4).
__global__ __launch_bounds__(256,2) void k_attn(
    const unsigned short* __restrict__ Q,
    const unsigned short* __restrict__ K,
    const unsigned short* __restrict__ Vt,
    unsigned short* __restrict__ ctx, int bshift, int hsh)
{
  __shared__ unsigned short KL[2][64*64];   // swizzled rows: kv x e
  __shared__ unsigned short VL[2][64*64];   // swizzled rows: d x kv
  __shared__ unsigned short Pl[4][2048];    // per-wave P [32 q][64 k], swizzled

  const int tid = threadIdx.x;
  const int w = tid >> 6, lane = tid & 63;
  const int lr = lane & 15, lhi = lane >> 4;

  const int lin = blockIdx.x;
  const int cc  = lin >> hsh;
  const int chunk = (cc < 8) ? cc : (23 - cc);
  const int hh  = lin & ((1 << hsh) - 1);
  const int q0  = chunk*128 + w*32;

  const unsigned short* Qh = Q  + (size_t)hh*S_LEN*HD;
  const unsigned short* Kh = K  + (size_t)hh*S_LEN*HD;
  const unsigned short* Vh = Vt + (size_t)hh*HD*S_LEN;
  unsigned short* Pw = Pl[w];

  // Q fragments (B-operand): lane(lr,lhi) holds Q[q0+qm*16+lr][kf*32+lhi*8+..]
  bf16x8 qf[2][2];
#pragma unroll
  for (int qm=0;qm<2;++qm)
#pragma unroll
    for (int kf=0;kf<2;++kf)
      qf[qm][kf] = *(const bf16x8*)&Qh[(size_t)(q0 + qm*16 + lr)*HD + kf*32 + lhi*8];

  f32x4 o[4][2];          // o[dn][qm]: O[q=q0+qm*16+lr][d=dn*16+lhi*4+r]
  float rm[2], rl[2];     // per q-col running max / sum
#pragma unroll
  for (int dn=0;dn<4;++dn)
#pragma unroll
    for (int qm=0;qm<2;++qm) o[dn][qm] = (f32x4){0.f,0.f,0.f,0.f};
  rm[0] = rm[1] = -3.0e38f;  rl[0] = rl[1] = 0.f;

  const int wtend = ((q0 + 31) >> 6) + 1;   // tiles this wave computes
  const int tmax  = 2*chunk + 2;            // tiles the block stages

  auto STAGE = [&](int tt, int bb2) {
    const int kv0 = tt*64;
#pragma unroll
    for (int j = 0; j < 2; ++j) {
      const int c   = j*256 + tid;
      const int row = c >> 3;
      const int sb  = (c*16) ^ ((row & 7) << 4);
      const int el  = (sb & 127) >> 1;
      const int ub  = (j*256 + (tid & 192)) * 16;
      GLOAD16(Kh + (size_t)(kv0+row)*HD + el,        (char*)KL[bb2] + ub);
      GLOAD16(Vh + (size_t)row*S_LEN + kv0 + el,     (char*)VL[bb2] + ub);
    }
  };

  STAGE(0, 0);
  int bb = 0;
  for (int t = 0; t < tmax; ++t) {
    if (t + 1 < tmax) {
      STAGE(t+1, bb^1);
      asm volatile("s_waitcnt vmcnt(4)" ::: "memory");   // cur tile landed
    } else {
      asm volatile("s_waitcnt vmcnt(0)" ::: "memory");
    }
    __builtin_amdgcn_s_barrier();

    if (t < wtend) {
      const int kv0 = t*64;
      const char* KB = (const char*)KL[bb];
      const char* VB = (const char*)VL[bb];

      // S^T[kn][qm]: lane holds k = kv0+kn*16+lhi*4+r, q = q0+qm*16+lr
      f32x4 st[4][2];
#pragma unroll
      for (int kn=0;kn<4;++kn)
#pragma unroll
        for (int qm=0;qm<2;++qm) st[kn][qm] = (f32x4){0.f,0.f,0.f,0.f};

#pragma unroll
      for (int kn=0;kn<4;++kn)
#pragma unroll
        for (int kf=0;kf<2;++kf) {
          const int row = kn*16 + lr;
          const int byt = ((row<<7) + kf*64 + lhi*16) ^ ((row & 7) << 4);
          const bf16x8 kfr = *(const bf16x8*)(KB + byt);   // A-frag: K rows
#pragma unroll
          for (int qm=0;qm<2;++qm)
            st[kn][qm] = __builtin_amdgcn_mfma_f32_16x16x32_bf16(kfr, qf[qm][kf], st[kn][qm], 0,0,0);
        }

      if (t == wtend-1) {   // diagonal tile: mask k > q
#pragma unroll
        for (int kn=0;kn<4;++kn)
#pragma unroll
          for (int qm=0;qm<2;++qm) {
            const int q = q0 + qm*16 + lr;
#pragma unroll
            for (int r=0;r<4;++r) {
              const int k = kv0 + kn*16 + lhi*4 + r;
              if (k > q) st[kn][qm][r] = -1.0e30f;
            }
          }
      }

      // in-register online softmax per q-col (2 shfl per reduce)
#pragma unroll
      for (int qm=0;qm<2;++qm) {
        float mx = st[0][qm][0];
#pragma unroll
        for (int kn=0;kn<4;++kn)
#pragma unroll
          for (int r=0;r<4;++r) mx = fmaxf(mx, st[kn][qm][r]);
        mx = fmaxf(mx, __shfl_xor(mx, 16));
        mx = fmaxf(mx, __shfl_xor(mx, 32));
        const float newm  = fmaxf(rm[qm], mx);
        const float alpha = __expf(rm[qm] - newm);
        rm[qm] = newm;
        float sum = 0.f;
#pragma unroll
        for (int kn=0;kn<4;++kn)
#pragma unroll
          for (int r=0;r<4;++r) {
            const float p = __expf(st[kn][qm][r] - newm);
            st[kn][qm][r] = p;
            sum += p;
          }
        sum += __shfl_xor(sum, 16);
        sum += __shfl_xor(sum, 32);
        rl[qm] = rl[qm]*alpha + sum;
#pragma unroll
        for (int dn=0;dn<4;++dn)
#pragma unroll
          for (int r=0;r<4;++r) o[dn][qm][r] *= alpha;
      }

      // P -> LDS: packed b64 writes (4 bf16 = consecutive k) to [q][k] tile
#pragma unroll
      for (int qm=0;qm<2;++qm) {
        const int qrow = qm*16 + lr;
#pragma unroll
        for (int kn=0;kn<4;++kn) {
          unsigned long long pk =
              (unsigned long long)f2bf(st[kn][qm][0])
            | ((unsigned long long)f2bf(st[kn][qm][1]) << 16)
            | ((unsigned long long)f2bf(st[kn][qm][2]) << 32)
            | ((unsigned long long)f2bf(st[kn][qm][3]) << 48);
          const int byt = (qrow*128 + kn*32 + lhi*8) ^ ((qrow & 7) << 4);
          *(unsigned long long*)((char*)Pw + byt) = pk;
        }
      }

      // PV: O^T[dn][qm] += MFMA(A = V^T rows, B = P rows)
#pragma unroll
      for (int ks=0;ks<2;++ks) {
        bf16x8 pfr[2];
#pragma unroll
        for (int qm=0;qm<2;++qm) {
          const int qrow = qm*16 + lr;
          const int byt = (qrow*128 + ks*64 + lhi*16) ^ ((qrow & 7) << 4);
          pfr[qm] = *(const bf16x8*)((char*)Pw + byt);     // B-frag: P rows
        }
#pragma unroll
        for (int dn=0;dn<4;++dn) {
          const int row = dn*16 + lr;
          const int byt = ((row<<7) + ks*64 + lhi*16) ^ ((row & 7) << 4);
          const bf16x8 vf = *(const bf16x8*)(VB + byt);    // A-frag: V^T rows
#pragma unroll
          for (int qm=0;qm<2;++qm)
            o[dn][qm] = __builtin_amdgcn_mfma_f32_16x16x32_bf16(vf, pfr[qm], o[dn][qm], 0,0,0);
        }
      }
    }
    __builtin_amdgcn_s_barrier();
    bb ^= 1;
  }

  const int h = hh & (NH-1);
  const int badd = hh >> 4;
#pragma unroll
  for (int qm=0;qm<2;++qm) {
    const float inv = 1.0f / rl[qm];
    const int q = q0 + qm*16 + lr;
    const size_t trow = ((size_t)q << bshift) + badd;
#pragma unroll
    for (int dn=0;dn<4;++dn) {
      unsigned long long pk =
          (unsigned long long)f2bf(o[dn][qm][0]*inv)
        | ((unsigned long long)f2bf(o[dn][qm][1]*inv) << 16)
        | ((unsigned long long)f2bf(o[dn][qm][2]*inv) << 32)
        | ((unsigned long long)f2bf(o[dn][qm][3]*inv) << 48);
      *(unsigned long long*)&ctx[trow*EMB + h*HD + dn*16 + lhi*4] = pk;
    }
  }
}

// ---------------- output projection ----------------
__global__ __launch_bounds__(256) void k_oproj(
    const unsigned short* __restrict__ ctxA,
    const float* __restrict__ wo,
    const float* __restrict__ bo,
    float* __restrict__ outb, int orm)
{
  __shared__ unsigned short Al[128*32];
  __shared__ unsigned short Bl[128*32];
  const int tid = threadIdx.x;
  const int m0 = blockIdx.x * 128;
  const int n0 = blockIdx.y * 128;
  const int w = tid >> 6, lane = tid & 63;
  const int wr = w >> 1, wc = w & 1;
  const int lr = lane & 15, lhi = lane >> 4;

  f32x4 acc[4][4];
#pragma unroll
  for (int m=0;m<4;++m)
#pragma unroll
    for (int n=0;n<4;++n) acc[m][n] = (f32x4){0.f,0.f,0.f,0.f};

  for (int k0 = 0; k0 < EMB; k0 += 32) {
    float4 b0[2], b1[2];
#pragma unroll
    for (int j = 0; j < 2; ++j) {
      const int c   = j*256 + tid;
      const int row = c >> 2;
      const int col = (c & 3) << 3;
      const float* bp = wo + (size_t)(n0+row)*EMB + k0 + col;
      b0[j] = *(const float4*)bp;  b1[j] = *(const float4*)(bp+4);
    }
    __syncthreads();
#pragma unroll
    for (int j = 0; j < 2; ++j) {
      const int c   = j*256 + tid;
      const int row = c >> 2;
      const int col = (c & 3) << 3;
      const int ub  = (j*256 + (tid & 192)) * 16;
      GLOAD16(ctxA + (size_t)(m0+row)*EMB + k0 + col, (char*)Al + ub);
      *(ushort8*)&Bl[row*32 + col] = cvt8(b0[j], b1[j]);
    }
    __syncthreads();
    bf16x8 af[4], bfr[4];
#pragma unroll
    for (int m=0;m<4;++m) af[m]  = *(const bf16x8*)&Al[(wr*64 + m*16 + lr)*32 + lhi*8];
#pragma unroll
    for (int n=0;n<4;++n) bfr[n] = *(const bf16x8*)&Bl[(wc*64 + n*16 + lr)*32 + lhi*8];
#pragma unroll
    for (int m=0;m<4;++m)
#pragma unroll
      for (int n=0;n<4;++n)
        acc[m][n] = __builtin_amdgcn_mfma_f32_16x16x32_bf16(af[m], bfr[n], acc[m][n], 0,0,0);
  }

#pragma unroll
  for (int m=0;m<4;++m)
#pragma unroll
    for (int n=0;n<4;++n)
#pragma unroll
      for (int r=0;r<4;++r) {
        const int rr   = m0 + wr*64 + m*16 + lhi*4 + r;
        const int fcol = n0 + wc*64 + n*16 + lr;
        outb[(size_t)rr*orm*EMB + fcol] = acc[m][n][r] + bo[fcol];
      }
}

// ---------------- launch ----------------
extern "C" void kernel_launch(void* const* d_in, const int* in_sizes, int n_in,
                              void* d_out, int out_size, void* d_ws, size_t ws_size,
                              hipStream_t stream) {
  const float* x  = (const float*)d_in[0];
  const float* wq = (const float*)d_in[1];
  const float* bq = (const float*)d_in[2];
  const float* wk = (const float*)d_in[3];
  const float* bk = (const float*)d_in[4];
  const float* wv = (const float*)d_in[5];
  const float* bv = (const float*)d_in[6];
  const float* wo = (const float*)d_in[7];
  const float* bo = (const float*)d_in[8];
  float* out = (float*)d_out;

  char* ws = (char*)d_ws;
  const size_t MB = (size_t)1 << 20;

  if (ws_size >= 32*MB) {
    unsigned short* Q  = (unsigned short*)(ws + 0*MB);
    unsigned short* K  = (unsigned short*)(ws + 8*MB);
    unsigned short* Vt = (unsigned short*)(ws + 16*MB);
    unsigned short* cx = (unsigned short*)(ws + 24*MB);
    k_qkv<<<dim3(32,8,3), 256, 0, stream>>>(x, EMB, 1, wq,wk,wv, bq,bk,bv, Q,K,Vt);
    k_attn<<<512, 256, 0, stream>>>(Q, K, Vt, cx, 1, 5);
    k_oproj<<<dim3(32,8), 256, 0, stream>>>(cx, wo, bo, out, 1);
  } else {
    unsigned short* Q  = (unsigned short*)(ws + 0*MB);
    unsigned short* K  = (unsigned short*)(ws + 4*MB);
    unsigned short* Vt = (unsigned short*)(ws + 8*MB);
    unsigned short* cx = (unsigned short*)(ws + 12*MB);
    for (int b = 0; b < 2; ++b) {
      k_qkv<<<dim3(16,8,3), 256, 0, stream>>>(x + b*EMB, 2*EMB, 0,
                                              wq,wk,wv, bq,bk,bv, Q,K,Vt);
      k_attn<<<256, 256, 0, stream>>>(Q, K, Vt, cx, 0, 4);
      k_oproj<<<dim3(16,8), 256, 0, stream>>>(cx, wo, bo, out + b*EMB, 2);
    }
  }
}

// Round 6
// 145.040 us; speedup vs baseline: 2.4957x; 1.2079x over previous
//
#include <hip/hip_runtime.h>
#include <hip/hip_bf16.h>
#include <stdint.h>

#define S_LEN 2048
#define BATCH 2
#define EMB   1024
#define NH    16
#define HD    64

typedef __bf16 bf16x8 __attribute__((ext_vector_type(8)));
typedef float  f32x4  __attribute__((ext_vector_type(4)));
typedef unsigned short ushort8 __attribute__((ext_vector_type(8)));

__device__ __forceinline__ unsigned short f2bf(float f) {
  unsigned int u = __float_as_uint(f);
  u += 0x7fffu + ((u >> 16) & 1u);
  return (unsigned short)(u >> 16);
}

__device__ __forceinline__ ushort8 cvt8(const float4 a, const float4 b) {
  ushort8 o;
  o[0]=f2bf(a.x); o[1]=f2bf(a.y); o[2]=f2bf(a.z); o[3]=f2bf(a.w);
  o[4]=f2bf(b.x); o[5]=f2bf(b.y); o[6]=f2bf(b.z); o[7]=f2bf(b.w);
  return o;
}

#define GLOAD16(g, l) __builtin_amdgcn_global_load_lds( \
    (const __attribute__((address_space(1))) void*)(g),  \
    (__attribute__((address_space(3))) void*)(l), 16, 0, 0)

// ---------------- fp32 -> bf16 conversion ----------------
__global__ __launch_bounds__(256) void k_cvt(const float* __restrict__ src,
                                             unsigned short* __restrict__ dst,
                                             int n) {
  int i = (blockIdx.x*256 + threadIdx.x)*8;
  if (i >= n) return;
  const float4* s4 = (const float4*)(src + i);
  *(ushort8*)(dst + i) = cvt8(s4[0], s4[1]);
}

// ---------------- QKV projection, bf16 A (merged path) ----------------
// A = xb bf16 [4096][1024] via global_load_lds; B = w fp32 reg-staged.
// 1D grid 768 blocks, XCD-grouped: same-m blocks contiguous per XCD.
__global__ __launch_bounds__(256) void k_qkv_bf(
    const unsigned short* __restrict__ xb,
    const float* __restrict__ wq, const float* __restrict__ wk,
    const float* __restrict__ wv,
    const float* __restrict__ bq, const float* __restrict__ bk,
    const float* __restrict__ bv,
    unsigned short* __restrict__ Qb, unsigned short* __restrict__ Kb,
    unsigned short* __restrict__ Vtb)
{
  __shared__ unsigned short Al[128*32];
  __shared__ unsigned short Bl[128*32];
  const int tid = threadIdx.x;
  const int lin  = blockIdx.x;
  const int wgid = (lin & 7)*96 + (lin >> 3);   // bijective XCD chunking
  const int mb   = wgid / 24;                   // 0..31  (m-panel)
  const int t    = wgid % 24;
  const int z    = t >> 3;                      // 0..2  (q,k,v)
  const int nb   = t & 7;                       // 0..7  (n-panel)
  const int m0 = mb * 128;
  const int n0 = nb * 128;
  const int w = tid >> 6, lane = tid & 63;
  const int wr = w >> 1, wc = w & 1;
  const int lr = lane & 15, lhi = lane >> 4;
  const float* wz = (z==0) ? wq : ((z==1) ? wk : wv);

  f32x4 acc[4][4];
#pragma unroll
  for (int m=0;m<4;++m)
#pragma unroll
    for (int n=0;n<4;++n) acc[m][n] = (f32x4){0.f,0.f,0.f,0.f};

  for (int k0 = 0; k0 < EMB; k0 += 32) {
    float4 b0[2], b1[2];
#pragma unroll
    for (int j = 0; j < 2; ++j) {
      const int c   = j*256 + tid;
      const int row = c >> 2;
      const int col = (c & 3) << 3;
      const float* bp = wz + (size_t)(n0+row)*EMB + k0 + col;
      b0[j] = *(const float4*)bp;  b1[j] = *(const float4*)(bp+4);
    }
    __syncthreads();
#pragma unroll
    for (int j = 0; j < 2; ++j) {
      const int c   = j*256 + tid;
      const int row = c >> 2;
      const int col = (c & 3) << 3;
      const int ub  = (j*256 + (tid & 192)) * 16;   // wave-uniform LDS base
      GLOAD16(xb + (size_t)(m0+row)*EMB + k0 + col, (char*)Al + ub);
      *(ushort8*)&Bl[row*32 + col] = cvt8(b0[j], b1[j]);
    }
    __syncthreads();
    bf16x8 af[4], bfr[4];
#pragma unroll
    for (int m=0;m<4;++m) af[m]  = *(const bf16x8*)&Al[(wr*64 + m*16 + lr)*32 + lhi*8];
#pragma unroll
    for (int n=0;n<4;++n) bfr[n] = *(const bf16x8*)&Bl[(wc*64 + n*16 + lr)*32 + lhi*8];
#pragma unroll
    for (int m=0;m<4;++m)
#pragma unroll
      for (int n=0;n<4;++n)
        acc[m][n] = __builtin_amdgcn_mfma_f32_16x16x32_bf16(af[m], bfr[n], acc[m][n], 0,0,0);
  }

  const float scale = (z==0) ? 0.125f : 1.0f;   // D^-0.5
  const float* bias = (z==0) ? bq : ((z==1) ? bk : bv);
#pragma unroll
  for (int m=0;m<4;++m)
#pragma unroll
    for (int n=0;n<4;++n)
#pragma unroll
      for (int r=0;r<4;++r) {
        const int rr   = m0 + wr*64 + m*16 + lhi*4 + r;
        const int fcol = n0 + wc*64 + n*16 + lr;
        const float v = (acc[m][n][r] + bias[fcol]) * scale;
        const unsigned short ov = f2bf(v);
        const int i = rr >> 1, bsel = rr & 1;      // token-major rows (i*2+b)
        const int h = fcol >> 6, d = fcol & 63;
        const int hh = bsel*NH + h;
        if (z == 0)      Qb [((size_t)hh*S_LEN + i)*HD + d] = ov;
        else if (z == 1) Kb [((size_t)hh*S_LEN + i)*HD + d] = ov;
        else             Vtb[((size_t)hh*HD + d)*S_LEN + i] = ov;
      }
}

// ---------------- QKV projection, fp32 A (small-ws fallback) ------------
__global__ __launch_bounds__(256) void k_qkv(
    const float* __restrict__ xA, int a_rs, int ishift,
    const float* __restrict__ wq, const float* __restrict__ wk,
    const float* __restrict__ wv,
    const float* __restrict__ bq, const float* __restrict__ bk,
    const float* __restrict__ bv,
    unsigned short* __restrict__ Qb, unsigned short* __restrict__ Kb,
    unsigned short* __restrict__ Vtb)
{
  __shared__ unsigned short Al[128*32];
  __shared__ unsigned short Bl[128*32];
  const int tid = threadIdx.x;
  const int z  = blockIdx.z;
  const int m0 = blockIdx.x * 128;
  const int n0 = blockIdx.y * 128;
  const int w = tid >> 6, lane = tid & 63;
  const int wr = w >> 1, wc = w & 1;
  const int lr = lane & 15, lhi = lane >> 4;
  const float* wz = (z==0) ? wq : ((z==1) ? wk : wv);

  f32x4 acc[4][4];
#pragma unroll
  for (int m=0;m<4;++m)
#pragma unroll
    for (int n=0;n<4;++n) acc[m][n] = (f32x4){0.f,0.f,0.f,0.f};

  for (int k0 = 0; k0 < EMB; k0 += 32) {
    float4 a0[2], a1[2], b0[2], b1[2];
#pragma unroll
    for (int j = 0; j < 2; ++j) {
      const int c   = j*256 + tid;
      const int row = c >> 2;
      const int col = (c & 3) << 3;
      const float* ap = xA + (size_t)(m0+row)*a_rs + k0 + col;
      const float* bp = wz + (size_t)(n0+row)*EMB + k0 + col;
      a0[j] = *(const float4*)ap;  a1[j] = *(const float4*)(ap+4);
      b0[j] = *(const float4*)bp;  b1[j] = *(const float4*)(bp+4);
    }
    __syncthreads();
#pragma unroll
    for (int j = 0; j < 2; ++j) {
      const int c   = j*256 + tid;
      const int row = c >> 2;
      const int col = (c & 3) << 3;
      *(ushort8*)&Al[row*32 + col] = cvt8(a0[j], a1[j]);
      *(ushort8*)&Bl[row*32 + col] = cvt8(b0[j], b1[j]);
    }
    __syncthreads();
    bf16x8 af[4], bfr[4];
#pragma unroll
    for (int m=0;m<4;++m) af[m]  = *(const bf16x8*)&Al[(wr*64 + m*16 + lr)*32 + lhi*8];
#pragma unroll
    for (int n=0;n<4;++n) bfr[n] = *(const bf16x8*)&Bl[(wc*64 + n*16 + lr)*32 + lhi*8];
#pragma unroll
    for (int m=0;m<4;++m)
#pragma unroll
      for (int n=0;n<4;++n)
        acc[m][n] = __builtin_amdgcn_mfma_f32_16x16x32_bf16(af[m], bfr[n], acc[m][n], 0,0,0);
  }

  const float scale = (z==0) ? 0.125f : 1.0f;
  const float* bias = (z==0) ? bq : ((z==1) ? bk : bv);
  const int bmask = (1 << ishift) - 1;
#pragma unroll
  for (int m=0;m<4;++m)
#pragma unroll
    for (int n=0;n<4;++n)
#pragma unroll
      for (int r=0;r<4;++r) {
        const int rr   = m0 + wr*64 + m*16 + lhi*4 + r;
        const int fcol = n0 + wc*64 + n*16 + lr;
        const float v = (acc[m][n][r] + bias[fcol]) * scale;
        const unsigned short ov = f2bf(v);
        const int i = rr >> ishift, bsel = rr & bmask;
        const int h = fcol >> 6, d = fcol & 63;
        const int hh = bsel*NH + h;
        if (z == 0)      Qb [((size_t)hh*S_LEN + i)*HD + d] = ov;
        else if (z == 1) Kb [((size_t)hh*S_LEN + i)*HD + d] = ov;
        else             Vtb[((size_t)hh*HD + d)*S_LEN + i] = ov;
      }
}

// ---------------- causal flash attention (swapped-QK^T, LDS-staged) -------
__global__ __launch_bounds__(256,2) void k_attn(
    const unsigned short* __restrict__ Q,
    const unsigned short* __restrict__ K,
    const unsigned short* __restrict__ Vt,
    unsigned short* __restrict__ ctx, int bshift, int hsh)
{
  __shared__ unsigned short KL[2][64*64];
  __shared__ unsigned short VL[2][64*64];
  __shared__ unsigned short Pl[4][2048];

  const int tid = threadIdx.x;
  const int w = tid >> 6, lane = tid & 63;
  const int lr = lane & 15, lhi = lane >> 4;

  const int lin = blockIdx.x;
  const int cc  = lin >> hsh;
  const int chunk = (cc < 8) ? cc : (23 - cc);
  const int hh  = lin & ((1 << hsh) - 1);
  const int q0  = chunk*128 + w*32;

  const unsigned short* Qh = Q  + (size_t)hh*S_LEN*HD;
  const unsigned short* Kh = K  + (size_t)hh*S_LEN*HD;
  const unsigned short* Vh = Vt + (size_t)hh*HD*S_LEN;
  unsigned short* Pw = Pl[w];

  bf16x8 qf[2][2];
#pragma unroll
  for (int qm=0;qm<2;++qm)
#pragma unroll
    for (int kf=0;kf<2;++kf)
      qf[qm][kf] = *(const bf16x8*)&Qh[(size_t)(q0 + qm*16 + lr)*HD + kf*32 + lhi*8];

  f32x4 o[4][2];
  float rm[2], rl[2];
#pragma unroll
  for (int dn=0;dn<4;++dn)
#pragma unroll
    for (int qm=0;qm<2;++qm) o[dn][qm] = (f32x4){0.f,0.f,0.f,0.f};
  rm[0] = rm[1] = -3.0e38f;  rl[0] = rl[1] = 0.f;

  const int wtend = ((q0 + 31) >> 6) + 1;
  const int tmax  = 2*chunk + 2;

  auto STAGE = [&](int tt, int bb2) {
    const int kv0 = tt*64;
#pragma unroll
    for (int j = 0; j < 2; ++j) {
      const int c   = j*256 + tid;
      const int row = c >> 3;
      const int sb  = (c*16) ^ ((row & 7) << 4);
      const int el  = (sb & 127) >> 1;
      const int ub  = (j*256 + (tid & 192)) * 16;
      GLOAD16(Kh + (size_t)(kv0+row)*HD + el,        (char*)KL[bb2] + ub);
      GLOAD16(Vh + (size_t)row*S_LEN + kv0 + el,     (char*)VL[bb2] + ub);
    }
  };

  STAGE(0, 0);
  int bb = 0;
  for (int t = 0; t < tmax; ++t) {
    if (t + 1 < tmax) {
      STAGE(t+1, bb^1);
      asm volatile("s_waitcnt vmcnt(4)" ::: "memory");
    } else {
      asm volatile("s_waitcnt vmcnt(0)" ::: "memory");
    }
    __builtin_amdgcn_s_barrier();

    if (t < wtend) {
      const int kv0 = t*64;
      const char* KB = (const char*)KL[bb];
      const char* VB = (const char*)VL[bb];

      f32x4 st[4][2];
#pragma unroll
      for (int kn=0;kn<4;++kn)
#pragma unroll
        for (int qm=0;qm<2;++qm) st[kn][qm] = (f32x4){0.f,0.f,0.f,0.f};

#pragma unroll
      for (int kn=0;kn<4;++kn)
#pragma unroll
        for (int kf=0;kf<2;++kf) {
          const int row = kn*16 + lr;
          const int byt = ((row<<7) + kf*64 + lhi*16) ^ ((row & 7) << 4);
          const bf16x8 kfr = *(const bf16x8*)(KB + byt);
#pragma unroll
          for (int qm=0;qm<2;++qm)
            st[kn][qm] = __builtin_amdgcn_mfma_f32_16x16x32_bf16(kfr, qf[qm][kf], st[kn][qm], 0,0,0);
        }

      if (t == wtend-1) {
#pragma unroll
        for (int kn=0;kn<4;++kn)
#pragma unroll
          for (int qm=0;qm<2;++qm) {
            const int q = q0 + qm*16 + lr;
#pragma unroll
            for (int r=0;r<4;++r) {
              const int k = kv0 + kn*16 + lhi*4 + r;
              if (k > q) st[kn][qm][r] = -1.0e30f;
            }
          }
      }

#pragma unroll
      for (int qm=0;qm<2;++qm) {
        float mx = st[0][qm][0];
#pragma unroll
        for (int kn=0;kn<4;++kn)
#pragma unroll
          for (int r=0;r<4;++r) mx = fmaxf(mx, st[kn][qm][r]);
        mx = fmaxf(mx, __shfl_xor(mx, 16));
        mx = fmaxf(mx, __shfl_xor(mx, 32));
        const float newm  = fmaxf(rm[qm], mx);
        const float alpha = __expf(rm[qm] - newm);
        rm[qm] = newm;
        float sum = 0.f;
#pragma unroll
        for (int kn=0;kn<4;++kn)
#pragma unroll
          for (int r=0;r<4;++r) {
            const float p = __expf(st[kn][qm][r] - newm);
            st[kn][qm][r] = p;
            sum += p;
          }
        sum += __shfl_xor(sum, 16);
        sum += __shfl_xor(sum, 32);
        rl[qm] = rl[qm]*alpha + sum;
#pragma unroll
        for (int dn=0;dn<4;++dn)
#pragma unroll
          for (int r=0;r<4;++r) o[dn][qm][r] *= alpha;
      }

#pragma unroll
      for (int qm=0;qm<2;++qm) {
        const int qrow = qm*16 + lr;
#pragma unroll
        for (int kn=0;kn<4;++kn) {
          unsigned long long pk =
              (unsigned long long)f2bf(st[kn][qm][0])
            | ((unsigned long long)f2bf(st[kn][qm][1]) << 16)
            | ((unsigned long long)f2bf(st[kn][qm][2]) << 32)
            | ((unsigned long long)f2bf(st[kn][qm][3]) << 48);
          const int byt = (qrow*128 + kn*32 + lhi*8) ^ ((qrow & 7) << 4);
          *(unsigned long long*)((char*)Pw + byt) = pk;
        }
      }

#pragma unroll
      for (int ks=0;ks<2;++ks) {
        bf16x8 pfr[2];
#pragma unroll
        for (int qm=0;qm<2;++qm) {
          const int qrow = qm*16 + lr;
          const int byt = (qrow*128 + ks*64 + lhi*16) ^ ((qrow & 7) << 4);
          pfr[qm] = *(const bf16x8*)((char*)Pw + byt);
        }
#pragma unroll
        for (int dn=0;dn<4;++dn) {
          const int row = dn*16 + lr;
          const int byt = ((row<<7) + ks*64 + lhi*16) ^ ((row & 7) << 4);
          const bf16x8 vf = *(const bf16x8*)(VB + byt);
#pragma unroll
          for (int qm=0;qm<2;++qm)
            o[dn][qm] = __builtin_amdgcn_mfma_f32_16x16x32_bf16(vf, pfr[qm], o[dn][qm], 0,0,0);
        }
      }
    }
    __builtin_amdgcn_s_barrier();
    bb ^= 1;
  }

  const int h = hh & (NH-1);
  const int badd = hh >> 4;
#pragma unroll
  for (int qm=0;qm<2;++qm) {
    const float inv = 1.0f / rl[qm];
    const int q = q0 + qm*16 + lr;
    const size_t trow = ((size_t)q << bshift) + badd;
#pragma unroll
    for (int dn=0;dn<4;++dn) {
      unsigned long long pk =
          (unsigned long long)f2bf(o[dn][qm][0]*inv)
        | ((unsigned long long)f2bf(o[dn][qm][1]*inv) << 16)
        | ((unsigned long long)f2bf(o[dn][qm][2]*inv) << 32)
        | ((unsigned long long)f2bf(o[dn][qm][3]*inv) << 48);
      *(unsigned long long*)&ctx[trow*EMB + h*HD + dn*16 + lhi*4] = pk;
    }
  }
}

// ---------------- output projection, bf16 A+B (merged path) --------------
__global__ __launch_bounds__(256) void k_oproj_bf(
    const unsigned short* __restrict__ ctxA,
    const unsigned short* __restrict__ wob,
    const float* __restrict__ bo,
    float* __restrict__ out)
{
  __shared__ unsigned short Al[128*32];
  __shared__ unsigned short Bl[128*32];
  const int tid = threadIdx.x;
  const int m0 = blockIdx.x * 128;
  const int n0 = blockIdx.y * 128;
  const int w = tid >> 6, lane = tid & 63;
  const int wr = w >> 1, wc = w & 1;
  const int lr = lane & 15, lhi = lane >> 4;

  f32x4 acc[4][4];
#pragma unroll
  for (int m=0;m<4;++m)
#pragma unroll
    for (int n=0;n<4;++n) acc[m][n] = (f32x4){0.f,0.f,0.f,0.f};

  for (int k0 = 0; k0 < EMB; k0 += 32) {
    __syncthreads();
#pragma unroll
    for (int j = 0; j < 2; ++j) {
      const int c   = j*256 + tid;
      const int row = c >> 2;
      const int col = (c & 3) << 3;
      const int ub  = (j*256 + (tid & 192)) * 16;
      GLOAD16(ctxA + (size_t)(m0+row)*EMB + k0 + col, (char*)Al + ub);
      GLOAD16(wob  + (size_t)(n0+row)*EMB + k0 + col, (char*)Bl + ub);
    }
    __syncthreads();
    bf16x8 af[4], bfr[4];
#pragma unroll
    for (int m=0;m<4;++m) af[m]  = *(const bf16x8*)&Al[(wr*64 + m*16 + lr)*32 + lhi*8];
#pragma unroll
    for (int n=0;n<4;++n) bfr[n] = *(const bf16x8*)&Bl[(wc*64 + n*16 + lr)*32 + lhi*8];
#pragma unroll
    for (int m=0;m<4;++m)
#pragma unroll
      for (int n=0;n<4;++n)
        acc[m][n] = __builtin_amdgcn_mfma_f32_16x16x32_bf16(af[m], bfr[n], acc[m][n], 0,0,0);
  }

#pragma unroll
  for (int m=0;m<4;++m)
#pragma unroll
    for (int n=0;n<4;++n)
#pragma unroll
      for (int r=0;r<4;++r) {
        const int rr   = m0 + wr*64 + m*16 + lhi*4 + r;
        const int fcol = n0 + wc*64 + n*16 + lr;
        out[(size_t)rr*EMB + fcol] = acc[m][n][r] + bo[fcol];
      }
}

// ---------------- output projection, fp32 B (fallback) -------------------
__global__ __launch_bounds__(256) void k_oproj(
    const unsigned short* __restrict__ ctxA,
    const float* __restrict__ wo,
    const float* __restrict__ bo,
    float* __restrict__ outb, int orm)
{
  __shared__ unsigned short Al[128*32];
  __shared__ unsigned short Bl[128*32];
  const int tid = threadIdx.x;
  const int m0 = blockIdx.x * 128;
  const int n0 = blockIdx.y * 128;
  const int w = tid >> 6, lane = tid & 63;
  const int wr = w >> 1, wc = w & 1;
  const int lr = lane & 15, lhi = lane >> 4;

  f32x4 acc[4][4];
#pragma unroll
  for (int m=0;m<4;++m)
#pragma unroll
    for (int n=0;n<4;++n) acc[m][n] = (f32x4){0.f,0.f,0.f,0.f};

  for (int k0 = 0; k0 < EMB; k0 += 32) {
    float4 b0[2], b1[2];
#pragma unroll
    for (int j = 0; j < 2; ++j) {
      const int c   = j*256 + tid;
      const int row = c >> 2;
      const int col = (c & 3) << 3;
      const float* bp = wo + (size_t)(n0+row)*EMB + k0 + col;
      b0[j] = *(const float4*)bp;  b1[j] = *(const float4*)(bp+4);
    }
    __syncthreads();
#pragma unroll
    for (int j = 0; j < 2; ++j) {
      const int c   = j*256 + tid;
      const int row = c >> 2;
      const int col = (c & 3) << 3;
      const int ub  = (j*256 + (tid & 192)) * 16;
      GLOAD16(ctxA + (size_t)(m0+row)*EMB + k0 + col, (char*)Al + ub);
      *(ushort8*)&Bl[row*32 + col] = cvt8(b0[j], b1[j]);
    }
    __syncthreads();
    bf16x8 af[4], bfr[4];
#pragma unroll
    for (int m=0;m<4;++m) af[m]  = *(const bf16x8*)&Al[(wr*64 + m*16 + lr)*32 + lhi*8];
#pragma unroll
    for (int n=0;n<4;++n) bfr[n] = *(const bf16x8*)&Bl[(wc*64 + n*16 + lr)*32 + lhi*8];
#pragma unroll
    for (int m=0;m<4;++m)
#pragma unroll
      for (int n=0;n<4;++n)
        acc[m][n] = __builtin_amdgcn_mfma_f32_16x16x32_bf16(af[m], bfr[n], acc[m][n], 0,0,0);
  }

#pragma unroll
  for (int m=0;m<4;++m)
#pragma unroll
    for (int n=0;n<4;++n)
#pragma unroll
      for (int r=0;r<4;++r) {
        const int rr   = m0 + wr*64 + m*16 + lhi*4 + r;
        const int fcol = n0 + wc*64 + n*16 + lr;
        outb[(size_t)rr*orm*EMB + fcol] = acc[m][n][r] + bo[fcol];
      }
}

// ---------------- launch ----------------
extern "C" void kernel_launch(void* const* d_in, const int* in_sizes, int n_in,
                              void* d_out, int out_size, void* d_ws, size_t ws_size,
                              hipStream_t stream) {
  const float* x  = (const float*)d_in[0];
  const float* wq = (const float*)d_in[1];
  const float* bq = (const float*)d_in[2];
  const float* wk = (const float*)d_in[3];
  const float* bk = (const float*)d_in[4];
  const float* wv = (const float*)d_in[5];
  const float* bv = (const float*)d_in[6];
  const float* wo = (const float*)d_in[7];
  const float* bo = (const float*)d_in[8];
  float* out = (float*)d_out;

  char* ws = (char*)d_ws;
  const size_t MB = (size_t)1 << 20;

  if (ws_size >= 32*MB) {
    unsigned short* Q   = (unsigned short*)(ws + 0*MB);
    unsigned short* K   = (unsigned short*)(ws + 8*MB);
    unsigned short* Vt  = (unsigned short*)(ws + 16*MB);
    unsigned short* cx  = (unsigned short*)(ws + 24*MB);  // aliases xb
    unsigned short* xb  = cx;                             // dead before attn writes cx
    unsigned short* wob = Vt;                             // Vt dead after attn

    k_cvt<<<2048, 256, 0, stream>>>(x, xb, (S_LEN*BATCH)*EMB);
    k_qkv_bf<<<768, 256, 0, stream>>>(xb, wq,wk,wv, bq,bk,bv, Q, K, Vt);
    k_attn<<<512, 256, 0, stream>>>(Q, K, Vt, cx, 1, 5);   // overwrites xb
    k_cvt<<<512, 256, 0, stream>>>(wo, wob, EMB*EMB);      // into dead Vt
    k_oproj_bf<<<dim3(32,8), 256, 0, stream>>>(cx, wob, bo, out);
  } else {
    unsigned short* Q  = (unsigned short*)(ws + 0*MB);
    unsigned short* K  = (unsigned short*)(ws + 4*MB);
    unsigned short* Vt = (unsigned short*)(ws + 8*MB);
    unsigned short* cx = (unsigned short*)(ws + 12*MB);
    for (int b = 0; b < 2; ++b) {
      k_qkv<<<dim3(16,8,3), 256, 0, stream>>>(x + b*EMB, 2*EMB, 0,
                                              wq,wk,wv, bq,bk,bv, Q,K,Vt);
      k_attn<<<256, 256, 0, stream>>>(Q, K, Vt, cx, 0, 4);
      k_oproj<<<dim3(16,8), 256, 0, stream>>>(cx, wo, bo, out + b*EMB, 2);
    }
  }
}

// Round 7
// 134.206 us; speedup vs baseline: 2.6971x; 1.0807x over previous
//
#include <hip/hip_runtime.h>
#include <hip/hip_bf16.h>
#include <stdint.h>

#define S_LEN 2048
#define BATCH 2
#define EMB   1024
#define NH    16
#define HD    64
#define LOG2E 1.4426950408889634f

typedef __bf16 bf16x8 __attribute__((ext_vector_type(8)));
typedef float  f32x4  __attribute__((ext_vector_type(4)));
typedef unsigned short ushort8 __attribute__((ext_vector_type(8)));

__device__ __forceinline__ unsigned short f2bf(float f) {
  unsigned int u = __float_as_uint(f);
  u += 0x7fffu + ((u >> 16) & 1u);
  return (unsigned short)(u >> 16);
}

__device__ __forceinline__ ushort8 cvt8(const float4 a, const float4 b) {
  ushort8 o;
  o[0]=f2bf(a.x); o[1]=f2bf(a.y); o[2]=f2bf(a.z); o[3]=f2bf(a.w);
  o[4]=f2bf(b.x); o[5]=f2bf(b.y); o[6]=f2bf(b.z); o[7]=f2bf(b.w);
  return o;
}

#define GLOAD16(g, l) __builtin_amdgcn_global_load_lds( \
    (const __attribute__((address_space(1))) void*)(g),  \
    (__attribute__((address_space(3))) void*)(l), 16, 0, 0)

// ---------------- fp32 -> bf16 conversion ----------------
__global__ __launch_bounds__(256) void k_cvt(const float* __restrict__ src,
                                             unsigned short* __restrict__ dst,
                                             int n) {
  int i = (blockIdx.x*256 + threadIdx.x)*8;
  if (i >= n) return;
  const float4* s4 = (const float4*)(src + i);
  *(ushort8*)(dst + i) = cvt8(s4[0], s4[1]);
}

// ---------------- QKV projection, bf16 A (merged path) ----------------
__global__ __launch_bounds__(256) void k_qkv_bf(
    const unsigned short* __restrict__ xb,
    const float* __restrict__ wq, const float* __restrict__ wk,
    const float* __restrict__ wv,
    const float* __restrict__ bq, const float* __restrict__ bk,
    const float* __restrict__ bv,
    unsigned short* __restrict__ Qb, unsigned short* __restrict__ Kb,
    unsigned short* __restrict__ Vtb)
{
  __shared__ unsigned short Al[128*32];
  __shared__ unsigned short Bl[128*32];
  const int tid = threadIdx.x;
  const int lin  = blockIdx.x;
  const int wgid = (lin & 7)*96 + (lin >> 3);   // bijective XCD chunking
  const int mb   = wgid / 24;
  const int t    = wgid % 24;
  const int z    = t >> 3;
  const int nb   = t & 7;
  const int m0 = mb * 128;
  const int n0 = nb * 128;
  const int w = tid >> 6, lane = tid & 63;
  const int wr = w >> 1, wc = w & 1;
  const int lr = lane & 15, lhi = lane >> 4;
  const float* wz = (z==0) ? wq : ((z==1) ? wk : wv);

  f32x4 acc[4][4];
#pragma unroll
  for (int m=0;m<4;++m)
#pragma unroll
    for (int n=0;n<4;++n) acc[m][n] = (f32x4){0.f,0.f,0.f,0.f};

  for (int k0 = 0; k0 < EMB; k0 += 32) {
    float4 b0[2], b1[2];
#pragma unroll
    for (int j = 0; j < 2; ++j) {
      const int c   = j*256 + tid;
      const int row = c >> 2;
      const int col = (c & 3) << 3;
      const float* bp = wz + (size_t)(n0+row)*EMB + k0 + col;
      b0[j] = *(const float4*)bp;  b1[j] = *(const float4*)(bp+4);
    }
    __syncthreads();
#pragma unroll
    for (int j = 0; j < 2; ++j) {
      const int c   = j*256 + tid;
      const int row = c >> 2;
      const int col = (c & 3) << 3;
      const int ub  = (j*256 + (tid & 192)) * 16;
      GLOAD16(xb + (size_t)(m0+row)*EMB + k0 + col, (char*)Al + ub);
      *(ushort8*)&Bl[row*32 + col] = cvt8(b0[j], b1[j]);
    }
    __syncthreads();
    bf16x8 af[4], bfr[4];
#pragma unroll
    for (int m=0;m<4;++m) af[m]  = *(const bf16x8*)&Al[(wr*64 + m*16 + lr)*32 + lhi*8];
#pragma unroll
    for (int n=0;n<4;++n) bfr[n] = *(const bf16x8*)&Bl[(wc*64 + n*16 + lr)*32 + lhi*8];
#pragma unroll
    for (int m=0;m<4;++m)
#pragma unroll
      for (int n=0;n<4;++n)
        acc[m][n] = __builtin_amdgcn_mfma_f32_16x16x32_bf16(af[m], bfr[n], acc[m][n], 0,0,0);
  }

  // Q carries D^-0.5 * log2(e) so attention softmax runs in exp2 domain
  const float scale = (z==0) ? 0.125f*LOG2E : 1.0f;
  const float* bias = (z==0) ? bq : ((z==1) ? bk : bv);
#pragma unroll
  for (int m=0;m<4;++m)
#pragma unroll
    for (int n=0;n<4;++n)
#pragma unroll
      for (int r=0;r<4;++r) {
        const int rr   = m0 + wr*64 + m*16 + lhi*4 + r;
        const int fcol = n0 + wc*64 + n*16 + lr;
        const float v = (acc[m][n][r] + bias[fcol]) * scale;
        const unsigned short ov = f2bf(v);
        const int i = rr >> 1, bsel = rr & 1;
        const int h = fcol >> 6, d = fcol & 63;
        const int hh = bsel*NH + h;
        if (z == 0)      Qb [((size_t)hh*S_LEN + i)*HD + d] = ov;
        else if (z == 1) Kb [((size_t)hh*S_LEN + i)*HD + d] = ov;
        else             Vtb[((size_t)hh*HD + d)*S_LEN + i] = ov;
      }
}

// ---------------- QKV projection, fp32 A (small-ws fallback) ------------
__global__ __launch_bounds__(256) void k_qkv(
    const float* __restrict__ xA, int a_rs, int ishift,
    const float* __restrict__ wq, const float* __restrict__ wk,
    const float* __restrict__ wv,
    const float* __restrict__ bq, const float* __restrict__ bk,
    const float* __restrict__ bv,
    unsigned short* __restrict__ Qb, unsigned short* __restrict__ Kb,
    unsigned short* __restrict__ Vtb)
{
  __shared__ unsigned short Al[128*32];
  __shared__ unsigned short Bl[128*32];
  const int tid = threadIdx.x;
  const int z  = blockIdx.z;
  const int m0 = blockIdx.x * 128;
  const int n0 = blockIdx.y * 128;
  const int w = tid >> 6, lane = tid & 63;
  const int wr = w >> 1, wc = w & 1;
  const int lr = lane & 15, lhi = lane >> 4;
  const float* wz = (z==0) ? wq : ((z==1) ? wk : wv);

  f32x4 acc[4][4];
#pragma unroll
  for (int m=0;m<4;++m)
#pragma unroll
    for (int n=0;n<4;++n) acc[m][n] = (f32x4){0.f,0.f,0.f,0.f};

  for (int k0 = 0; k0 < EMB; k0 += 32) {
    float4 a0[2], a1[2], b0[2], b1[2];
#pragma unroll
    for (int j = 0; j < 2; ++j) {
      const int c   = j*256 + tid;
      const int row = c >> 2;
      const int col = (c & 3) << 3;
      const float* ap = xA + (size_t)(m0+row)*a_rs + k0 + col;
      const float* bp = wz + (size_t)(n0+row)*EMB + k0 + col;
      a0[j] = *(const float4*)ap;  a1[j] = *(const float4*)(ap+4);
      b0[j] = *(const float4*)bp;  b1[j] = *(const float4*)(bp+4);
    }
    __syncthreads();
#pragma unroll
    for (int j = 0; j < 2; ++j) {
      const int c   = j*256 + tid;
      const int row = c >> 2;
      const int col = (c & 3) << 3;
      *(ushort8*)&Al[row*32 + col] = cvt8(a0[j], a1[j]);
      *(ushort8*)&Bl[row*32 + col] = cvt8(b0[j], b1[j]);
    }
    __syncthreads();
    bf16x8 af[4], bfr[4];
#pragma unroll
    for (int m=0;m<4;++m) af[m]  = *(const bf16x8*)&Al[(wr*64 + m*16 + lr)*32 + lhi*8];
#pragma unroll
    for (int n=0;n<4;++n) bfr[n] = *(const bf16x8*)&Bl[(wc*64 + n*16 + lr)*32 + lhi*8];
#pragma unroll
    for (int m=0;m<4;++m)
#pragma unroll
      for (int n=0;n<4;++n)
        acc[m][n] = __builtin_amdgcn_mfma_f32_16x16x32_bf16(af[m], bfr[n], acc[m][n], 0,0,0);
  }

  const float scale = (z==0) ? 0.125f*LOG2E : 1.0f;
  const float* bias = (z==0) ? bq : ((z==1) ? bk : bv);
  const int bmask = (1 << ishift) - 1;
#pragma unroll
  for (int m=0;m<4;++m)
#pragma unroll
    for (int n=0;n<4;++n)
#pragma unroll
      for (int r=0;r<4;++r) {
        const int rr   = m0 + wr*64 + m*16 + lhi*4 + r;
        const int fcol = n0 + wc*64 + n*16 + lr;
        const float v = (acc[m][n][r] + bias[fcol]) * scale;
        const unsigned short ov = f2bf(v);
        const int i = rr >> ishift, bsel = rr & bmask;
        const int h = fcol >> 6, d = fcol & 63;
        const int hh = bsel*NH + h;
        if (z == 0)      Qb [((size_t)hh*S_LEN + i)*HD + d] = ov;
        else if (z == 1) Kb [((size_t)hh*S_LEN + i)*HD + d] = ov;
        else             Vtb[((size_t)hh*HD + d)*S_LEN + i] = ov;
      }
}

// ---------------- causal flash attention ----------------
// 64-row blocks (4 waves x 16 q-rows), 40 KB LDS -> 4 blocks/CU.
// chunk map cc<16?cc:47-cc keeps per-CU work constant under round-robin.
// Swapped QK^T, exp2-domain softmax, defer-max (THR=8), setprio on MFMA.
__global__ __launch_bounds__(256,4) void k_attn(
    const unsigned short* __restrict__ Q,
    const unsigned short* __restrict__ K,
    const unsigned short* __restrict__ Vt,
    unsigned short* __restrict__ ctx, int bshift, int hsh)
{
  __shared__ unsigned short KL[2][64*64];
  __shared__ unsigned short VL[2][64*64];
  __shared__ unsigned short Pl[4][1024];   // per-wave P [16 q][64 k], swizzled

  const int tid = threadIdx.x;
  const int w = tid >> 6, lane = tid & 63;
  const int lr = lane & 15, lhi = lane >> 4;

  const int lin = blockIdx.x;
  const int cc  = lin >> hsh;
  const int chunk = (cc < 16) ? cc : (47 - cc);
  const int hh  = lin & ((1 << hsh) - 1);
  const int q0  = chunk*64 + w*16;

  const unsigned short* Qh = Q  + (size_t)hh*S_LEN*HD;
  const unsigned short* Kh = K  + (size_t)hh*S_LEN*HD;
  const unsigned short* Vh = Vt + (size_t)hh*HD*S_LEN;
  unsigned short* Pw = Pl[w];

  bf16x8 qf[2];
#pragma unroll
  for (int kf=0;kf<2;++kf)
    qf[kf] = *(const bf16x8*)&Qh[(size_t)(q0 + lr)*HD + kf*32 + lhi*8];

  f32x4 o[4];
  float rm = -3.0e38f, rl = 0.f;
#pragma unroll
  for (int dn=0;dn<4;++dn) o[dn] = (f32x4){0.f,0.f,0.f,0.f};

  const int tmax = chunk + 1;   // all 4 waves need tiles 0..chunk

  auto STAGE = [&](int tt, int bb2) {
    const int kv0 = tt*64;
#pragma unroll
    for (int j = 0; j < 2; ++j) {
      const int c   = j*256 + tid;
      const int row = c >> 3;
      const int sb  = (c*16) ^ ((row & 7) << 4);
      const int el  = (sb & 127) >> 1;
      const int ub  = (j*256 + (tid & 192)) * 16;
      GLOAD16(Kh + (size_t)(kv0+row)*HD + el,        (char*)KL[bb2] + ub);
      GLOAD16(Vh + (size_t)row*S_LEN + kv0 + el,     (char*)VL[bb2] + ub);
    }
  };

  STAGE(0, 0);
  int bb = 0;
  for (int t = 0; t < tmax; ++t) {
    if (t + 1 < tmax) {
      STAGE(t+1, bb^1);
      asm volatile("s_waitcnt vmcnt(4)" ::: "memory");
    } else {
      asm volatile("s_waitcnt vmcnt(0)" ::: "memory");
    }
    __builtin_amdgcn_s_barrier();

    const int kv0 = t*64;
    const char* KB = (const char*)KL[bb];
    const char* VB = (const char*)VL[bb];

    // S^T: lane holds k = kv0+kn*16+lhi*4+r, q = q0+lr
    f32x4 st[4];
#pragma unroll
    for (int kn=0;kn<4;++kn) st[kn] = (f32x4){0.f,0.f,0.f,0.f};

    __builtin_amdgcn_s_setprio(1);
#pragma unroll
    for (int kn=0;kn<4;++kn)
#pragma unroll
      for (int kf=0;kf<2;++kf) {
        const int row = kn*16 + lr;
        const int byt = ((row<<7) + kf*64 + lhi*16) ^ ((row & 7) << 4);
        const bf16x8 kfr = *(const bf16x8*)(KB + byt);
        st[kn] = __builtin_amdgcn_mfma_f32_16x16x32_bf16(kfr, qf[kf], st[kn], 0,0,0);
      }
    __builtin_amdgcn_s_setprio(0);

    if (t == tmax-1) {   // diagonal tile: mask k > q
      const int q = q0 + lr;
#pragma unroll
      for (int kn=0;kn<4;++kn)
#pragma unroll
        for (int r=0;r<4;++r) {
          const int k = kv0 + kn*16 + lhi*4 + r;
          if (k > q) st[kn][r] = -1.0e30f;
        }
    }

    // online softmax in exp2 domain; defer-max THR=8
    float mx = fmaxf(fmaxf(st[0][0], st[0][1]), fmaxf(st[0][2], st[0][3]));
#pragma unroll
    for (int kn=1;kn<4;++kn)
      mx = fmaxf(mx, fmaxf(fmaxf(st[kn][0], st[kn][1]),
                           fmaxf(st[kn][2], st[kn][3])));
    mx = fmaxf(mx, __shfl_xor(mx, 16));
    mx = fmaxf(mx, __shfl_xor(mx, 32));
    if (!__all(mx - rm <= 8.0f)) {
      const float newm  = fmaxf(rm, mx);
      const float alpha = exp2f(rm - newm);
      rl *= alpha;
#pragma unroll
      for (int dn=0;dn<4;++dn)
#pragma unroll
        for (int r=0;r<4;++r) o[dn][r] *= alpha;
      rm = newm;
    }
    float sum = 0.f;
#pragma unroll
    for (int kn=0;kn<4;++kn)
#pragma unroll
      for (int r=0;r<4;++r) {
        const float p = exp2f(st[kn][r] - rm);
        st[kn][r] = p;
        sum += p;
      }
    sum += __shfl_xor(sum, 16);
    sum += __shfl_xor(sum, 32);
    rl += sum;

    // P -> LDS: packed b64 (4 bf16 = consecutive k), swizzled [16 q][64 k]
    {
      const int qrow = lr;
#pragma unroll
      for (int kn=0;kn<4;++kn) {
        unsigned long long pk =
            (unsigned long long)f2bf(st[kn][0])
          | ((unsigned long long)f2bf(st[kn][1]) << 16)
          | ((unsigned long long)f2bf(st[kn][2]) << 32)
          | ((unsigned long long)f2bf(st[kn][3]) << 48);
        const int byt = (qrow*128 + kn*32 + lhi*8) ^ ((qrow & 7) << 4);
        *(unsigned long long*)((char*)Pw + byt) = pk;
      }
    }

    // PV: O^T += MFMA(A = V^T rows, B = P rows)
#pragma unroll
    for (int ks=0;ks<2;++ks) {
      const int qrow = lr;
      const int pby = (qrow*128 + ks*64 + lhi*16) ^ ((qrow & 7) << 4);
      const bf16x8 pfr = *(const bf16x8*)((char*)Pw + pby);
      __builtin_amdgcn_s_setprio(1);
#pragma unroll
      for (int dn=0;dn<4;++dn) {
        const int row = dn*16 + lr;
        const int byt = ((row<<7) + ks*64 + lhi*16) ^ ((row & 7) << 4);
        const bf16x8 vf = *(const bf16x8*)(VB + byt);
        o[dn] = __builtin_amdgcn_mfma_f32_16x16x32_bf16(vf, pfr, o[dn], 0,0,0);
      }
      __builtin_amdgcn_s_setprio(0);
    }

    __builtin_amdgcn_s_barrier();
    bb ^= 1;
  }

  const int h = hh & (NH-1);
  const int badd = hh >> 4;
  const float inv = 1.0f / rl;
  const int q = q0 + lr;
  const size_t trow = ((size_t)q << bshift) + badd;
#pragma unroll
  for (int dn=0;dn<4;++dn) {
    unsigned long long pk =
        (unsigned long long)f2bf(o[dn][0]*inv)
      | ((unsigned long long)f2bf(o[dn][1]*inv) << 16)
      | ((unsigned long long)f2bf(o[dn][2]*inv) << 32)
      | ((unsigned long long)f2bf(o[dn][3]*inv) << 48);
    *(unsigned long long*)&ctx[trow*EMB + h*HD + dn*16 + lhi*4] = pk;
  }
}

// ---------------- output projection, bf16 A+B (merged path) --------------
__global__ __launch_bounds__(256) void k_oproj_bf(
    const unsigned short* __restrict__ ctxA,
    const unsigned short* __restrict__ wob,
    const float* __restrict__ bo,
    float* __restrict__ out)
{
  __shared__ unsigned short Al[128*32];
  __shared__ unsigned short Bl[128*32];
  const int tid = threadIdx.x;
  const int m0 = blockIdx.x * 128;
  const int n0 = blockIdx.y * 128;
  const int w = tid >> 6, lane = tid & 63;
  const int wr = w >> 1, wc = w & 1;
  const int lr = lane & 15, lhi = lane >> 4;

  f32x4 acc[4][4];
#pragma unroll
  for (int m=0;m<4;++m)
#pragma unroll
    for (int n=0;n<4;++n) acc[m][n] = (f32x4){0.f,0.f,0.f,0.f};

  for (int k0 = 0; k0 < EMB; k0 += 32) {
    __syncthreads();
#pragma unroll
    for (int j = 0; j < 2; ++j) {
      const int c   = j*256 + tid;
      const int row = c >> 2;
      const int col = (c & 3) << 3;
      const int ub  = (j*256 + (tid & 192)) * 16;
      GLOAD16(ctxA + (size_t)(m0+row)*EMB + k0 + col, (char*)Al + ub);
      GLOAD16(wob  + (size_t)(n0+row)*EMB + k0 + col, (char*)Bl + ub);
    }
    __syncthreads();
    bf16x8 af[4], bfr[4];
#pragma unroll
    for (int m=0;m<4;++m) af[m]  = *(const bf16x8*)&Al[(wr*64 + m*16 + lr)*32 + lhi*8];
#pragma unroll
    for (int n=0;n<4;++n) bfr[n] = *(const bf16x8*)&Bl[(wc*64 + n*16 + lr)*32 + lhi*8];
#pragma unroll
    for (int m=0;m<4;++m)
#pragma unroll
      for (int n=0;n<4;++n)
        acc[m][n] = __builtin_amdgcn_mfma_f32_16x16x32_bf16(af[m], bfr[n], acc[m][n], 0,0,0);
  }

#pragma unroll
  for (int m=0;m<4;++m)
#pragma unroll
    for (int n=0;n<4;++n)
#pragma unroll
      for (int r=0;r<4;++r) {
        const int rr   = m0 + wr*64 + m*16 + lhi*4 + r;
        const int fcol = n0 + wc*64 + n*16 + lr;
        out[(size_t)rr*EMB + fcol] = acc[m][n][r] + bo[fcol];
      }
}

// ---------------- output projection, fp32 B (fallback) -------------------
__global__ __launch_bounds__(256) void k_oproj(
    const unsigned short* __restrict__ ctxA,
    const float* __restrict__ wo,
    const float* __restrict__ bo,
    float* __restrict__ outb, int orm)
{
  __shared__ unsigned short Al[128*32];
  __shared__ unsigned short Bl[128*32];
  const int tid = threadIdx.x;
  const int m0 = blockIdx.x * 128;
  const int n0 = blockIdx.y * 128;
  const int w = tid >> 6, lane = tid & 63;
  const int wr = w >> 1, wc = w & 1;
  const int lr = lane & 15, lhi = lane >> 4;

  f32x4 acc[4][4];
#pragma unroll
  for (int m=0;m<4;++m)
#pragma unroll
    for (int n=0;n<4;++n) acc[m][n] = (f32x4){0.f,0.f,0.f,0.f};

  for (int k0 = 0; k0 < EMB; k0 += 32) {
    float4 b0[2], b1[2];
#pragma unroll
    for (int j = 0; j < 2; ++j) {
      const int c   = j*256 + tid;
      const int row = c >> 2;
      const int col = (c & 3) << 3;
      const float* bp = wo + (size_t)(n0+row)*EMB + k0 + col;
      b0[j] = *(const float4*)bp;  b1[j] = *(const float4*)(bp+4);
    }
    __syncthreads();
#pragma unroll
    for (int j = 0; j < 2; ++j) {
      const int c   = j*256 + tid;
      const int row = c >> 2;
      const int col = (c & 3) << 3;
      const int ub  = (j*256 + (tid & 192)) * 16;
      GLOAD16(ctxA + (size_t)(m0+row)*EMB + k0 + col, (char*)Al + ub);
      *(ushort8*)&Bl[row*32 + col] = cvt8(b0[j], b1[j]);
    }
    __syncthreads();
    bf16x8 af[4], bfr[4];
#pragma unroll
    for (int m=0;m<4;++m) af[m]  = *(const bf16x8*)&Al[(wr*64 + m*16 + lr)*32 + lhi*8];
#pragma unroll
    for (int n=0;n<4;++n) bfr[n] = *(const bf16x8*)&Bl[(wc*64 + n*16 + lr)*32 + lhi*8];
#pragma unroll
    for (int m=0;m<4;++m)
#pragma unroll
      for (int n=0;n<4;++n)
        acc[m][n] = __builtin_amdgcn_mfma_f32_16x16x32_bf16(af[m], bfr[n], acc[m][n], 0,0,0);
  }

#pragma unroll
  for (int m=0;m<4;++m)
#pragma unroll
    for (int n=0;n<4;++n)
#pragma unroll
      for (int r=0;r<4;++r) {
        const int rr   = m0 + wr*64 + m*16 + lhi*4 + r;
        const int fcol = n0 + wc*64 + n*16 + lr;
        outb[(size_t)rr*orm*EMB + fcol] = acc[m][n][r] + bo[fcol];
      }
}

// ---------------- launch ----------------
extern "C" void kernel_launch(void* const* d_in, const int* in_sizes, int n_in,
                              void* d_out, int out_size, void* d_ws, size_t ws_size,
                              hipStream_t stream) {
  const float* x  = (const float*)d_in[0];
  const float* wq = (const float*)d_in[1];
  const float* bq = (const float*)d_in[2];
  const float* wk = (const float*)d_in[3];
  const float* bk = (const float*)d_in[4];
  const float* wv = (const float*)d_in[5];
  const float* bv = (const float*)d_in[6];
  const float* wo = (const float*)d_in[7];
  const float* bo = (const float*)d_in[8];
  float* out = (float*)d_out;

  char* ws = (char*)d_ws;
  const size_t MB = (size_t)1 << 20;

  if (ws_size >= 32*MB) {
    unsigned short* Q   = (unsigned short*)(ws + 0*MB);
    unsigned short* K   = (unsigned short*)(ws + 8*MB);
    unsigned short* Vt  = (unsigned short*)(ws + 16*MB);
    unsigned short* cx  = (unsigned short*)(ws + 24*MB);
    unsigned short* xb  = cx;        // dead before attn writes cx
    unsigned short* wob = Vt;        // Vt dead after attn

    k_cvt<<<2048, 256, 0, stream>>>(x, xb, (S_LEN*BATCH)*EMB);
    k_qkv_bf<<<768, 256, 0, stream>>>(xb, wq,wk,wv, bq,bk,bv, Q, K, Vt);
    k_attn<<<1024, 256, 0, stream>>>(Q, K, Vt, cx, 1, 5);
    k_cvt<<<512, 256, 0, stream>>>(wo, wob, EMB*EMB);
    k_oproj_bf<<<dim3(32,8), 256, 0, stream>>>(cx, wob, bo, out);
  } else {
    unsigned short* Q  = (unsigned short*)(ws + 0*MB);
    unsigned short* K  = (unsigned short*)(ws + 4*MB);
    unsigned short* Vt = (unsigned short*)(ws + 8*MB);
    unsigned short* cx = (unsigned short*)(ws + 12*MB);
    for (int b = 0; b < 2; ++b) {
      k_qkv<<<dim3(16,8,3), 256, 0, stream>>>(x + b*EMB, 2*EMB, 0,
                                              wq,wk,wv, bq,bk,bv, Q,K,Vt);
      k_attn<<<512, 256, 0, stream>>>(Q, K, Vt, cx, 0, 4);
      k_oproj<<<dim3(16,8), 256, 0, stream>>>(cx, wo, bo, out + b*EMB, 2);
    }
  }
}

// Round 8
// 131.740 us; speedup vs baseline: 2.7476x; 1.0187x over previous
//
#include <hip/hip_runtime.h>
#include <hip/hip_bf16.h>
#include <stdint.h>

#define S_LEN 2048
#define BATCH 2
#define EMB   1024
#define NH    16
#define HD    64
#define LOG2E 1.4426950408889634f

typedef __bf16 bf16x8 __attribute__((ext_vector_type(8)));
typedef float  f32x4  __attribute__((ext_vector_type(4)));
typedef unsigned short ushort8 __attribute__((ext_vector_type(8)));

// native cast -> v_cvt_pk_bf16_f32 (guide m240: scalar cast beats hand-rolled)
__device__ __forceinline__ unsigned short f2bf(float f) {
  __bf16 h = (__bf16)f;
  return __builtin_bit_cast(unsigned short, h);
}

__device__ __forceinline__ ushort8 cvt8(const float4 a, const float4 b) {
  ushort8 o;
  o[0]=f2bf(a.x); o[1]=f2bf(a.y); o[2]=f2bf(a.z); o[3]=f2bf(a.w);
  o[4]=f2bf(b.x); o[5]=f2bf(b.y); o[6]=f2bf(b.z); o[7]=f2bf(b.w);
  return o;
}

#define GLOAD16(g, l) __builtin_amdgcn_global_load_lds( \
    (const __attribute__((address_space(1))) void*)(g),  \
    (__attribute__((address_space(3))) void*)(l), 16, 0, 0)

// ---------------- fp32 -> bf16 conversion ----------------
__global__ __launch_bounds__(256) void k_cvt(const float* __restrict__ src,
                                             unsigned short* __restrict__ dst,
                                             int n) {
  int i = (blockIdx.x*256 + threadIdx.x)*8;
  if (i >= n) return;
  const float4* s4 = (const float4*)(src + i);
  *(ushort8*)(dst + i) = cvt8(s4[0], s4[1]);
}

// ---------------- QKV projection, A+B bf16 (big-ws tier) ----------------
// A = xb bf16, B = wb bf16 [3][1024][1024]; both via global_load_lds.
__global__ __launch_bounds__(256) void k_qkv_bb(
    const unsigned short* __restrict__ xb,
    const unsigned short* __restrict__ wb,
    const float* __restrict__ bq, const float* __restrict__ bk,
    const float* __restrict__ bv,
    unsigned short* __restrict__ Qb, unsigned short* __restrict__ Kb,
    unsigned short* __restrict__ Vtb)
{
  __shared__ unsigned short Al[128*32];
  __shared__ unsigned short Bl[128*32];
  const int tid = threadIdx.x;
  const int lin  = blockIdx.x;
  const int wgid = (lin & 7)*96 + (lin >> 3);   // bijective XCD chunking
  const int mb   = wgid / 24;
  const int t    = wgid % 24;
  const int z    = t >> 3;
  const int nb   = t & 7;
  const int m0 = mb * 128;
  const int n0 = nb * 128;
  const int w = tid >> 6, lane = tid & 63;
  const int wr = w >> 1, wc = w & 1;
  const int lr = lane & 15, lhi = lane >> 4;
  const unsigned short* wz = wb + (size_t)z * (EMB*EMB);

  f32x4 acc[4][4];
#pragma unroll
  for (int m=0;m<4;++m)
#pragma unroll
    for (int n=0;n<4;++n) acc[m][n] = (f32x4){0.f,0.f,0.f,0.f};

  for (int k0 = 0; k0 < EMB; k0 += 32) {
    __syncthreads();
#pragma unroll
    for (int j = 0; j < 2; ++j) {
      const int c   = j*256 + tid;
      const int row = c >> 2;
      const int col = (c & 3) << 3;
      const int ub  = (j*256 + (tid & 192)) * 16;
      GLOAD16(xb + (size_t)(m0+row)*EMB + k0 + col, (char*)Al + ub);
      GLOAD16(wz + (size_t)(n0+row)*EMB + k0 + col, (char*)Bl + ub);
    }
    __syncthreads();
    bf16x8 af[4], bfr[4];
#pragma unroll
    for (int m=0;m<4;++m) af[m]  = *(const bf16x8*)&Al[(wr*64 + m*16 + lr)*32 + lhi*8];
#pragma unroll
    for (int n=0;n<4;++n) bfr[n] = *(const bf16x8*)&Bl[(wc*64 + n*16 + lr)*32 + lhi*8];
#pragma unroll
    for (int m=0;m<4;++m)
#pragma unroll
      for (int n=0;n<4;++n)
        acc[m][n] = __builtin_amdgcn_mfma_f32_16x16x32_bf16(af[m], bfr[n], acc[m][n], 0,0,0);
  }

  const float scale = (z==0) ? 0.125f*LOG2E : 1.0f;
  const float* bias = (z==0) ? bq : ((z==1) ? bk : bv);
#pragma unroll
  for (int m=0;m<4;++m)
#pragma unroll
    for (int n=0;n<4;++n)
#pragma unroll
      for (int r=0;r<4;++r) {
        const int rr   = m0 + wr*64 + m*16 + lhi*4 + r;
        const int fcol = n0 + wc*64 + n*16 + lr;
        const float v = (acc[m][n][r] + bias[fcol]) * scale;
        const unsigned short ov = f2bf(v);
        const int i = rr >> 1, bsel = rr & 1;
        const int h = fcol >> 6, d = fcol & 63;
        const int hh = bsel*NH + h;
        if (z == 0)      Qb [((size_t)hh*S_LEN + i)*HD + d] = ov;
        else if (z == 1) Kb [((size_t)hh*S_LEN + i)*HD + d] = ov;
        else             Vtb[((size_t)hh*HD + d)*S_LEN + i] = ov;
      }
}

// ---------------- QKV projection, bf16 A / fp32 B (32MB tier) ------------
__global__ __launch_bounds__(256) void k_qkv_bf(
    const unsigned short* __restrict__ xb,
    const float* __restrict__ wq, const float* __restrict__ wk,
    const float* __restrict__ wv,
    const float* __restrict__ bq, const float* __restrict__ bk,
    const float* __restrict__ bv,
    unsigned short* __restrict__ Qb, unsigned short* __restrict__ Kb,
    unsigned short* __restrict__ Vtb)
{
  __shared__ unsigned short Al[128*32];
  __shared__ unsigned short Bl[128*32];
  const int tid = threadIdx.x;
  const int lin  = blockIdx.x;
  const int wgid = (lin & 7)*96 + (lin >> 3);
  const int mb   = wgid / 24;
  const int t    = wgid % 24;
  const int z    = t >> 3;
  const int nb   = t & 7;
  const int m0 = mb * 128;
  const int n0 = nb * 128;
  const int w = tid >> 6, lane = tid & 63;
  const int wr = w >> 1, wc = w & 1;
  const int lr = lane & 15, lhi = lane >> 4;
  const float* wz = (z==0) ? wq : ((z==1) ? wk : wv);

  f32x4 acc[4][4];
#pragma unroll
  for (int m=0;m<4;++m)
#pragma unroll
    for (int n=0;n<4;++n) acc[m][n] = (f32x4){0.f,0.f,0.f,0.f};

  for (int k0 = 0; k0 < EMB; k0 += 32) {
    float4 b0[2], b1[2];
#pragma unroll
    for (int j = 0; j < 2; ++j) {
      const int c   = j*256 + tid;
      const int row = c >> 2;
      const int col = (c & 3) << 3;
      const float* bp = wz + (size_t)(n0+row)*EMB + k0 + col;
      b0[j] = *(const float4*)bp;  b1[j] = *(const float4*)(bp+4);
    }
    __syncthreads();
#pragma unroll
    for (int j = 0; j < 2; ++j) {
      const int c   = j*256 + tid;
      const int row = c >> 2;
      const int col = (c & 3) << 3;
      const int ub  = (j*256 + (tid & 192)) * 16;
      GLOAD16(xb + (size_t)(m0+row)*EMB + k0 + col, (char*)Al + ub);
      *(ushort8*)&Bl[row*32 + col] = cvt8(b0[j], b1[j]);
    }
    __syncthreads();
    bf16x8 af[4], bfr[4];
#pragma unroll
    for (int m=0;m<4;++m) af[m]  = *(const bf16x8*)&Al[(wr*64 + m*16 + lr)*32 + lhi*8];
#pragma unroll
    for (int n=0;n<4;++n) bfr[n] = *(const bf16x8*)&Bl[(wc*64 + n*16 + lr)*32 + lhi*8];
#pragma unroll
    for (int m=0;m<4;++m)
#pragma unroll
      for (int n=0;n<4;++n)
        acc[m][n] = __builtin_amdgcn_mfma_f32_16x16x32_bf16(af[m], bfr[n], acc[m][n], 0,0,0);
  }

  const float scale = (z==0) ? 0.125f*LOG2E : 1.0f;
  const float* bias = (z==0) ? bq : ((z==1) ? bk : bv);
#pragma unroll
  for (int m=0;m<4;++m)
#pragma unroll
    for (int n=0;n<4;++n)
#pragma unroll
      for (int r=0;r<4;++r) {
        const int rr   = m0 + wr*64 + m*16 + lhi*4 + r;
        const int fcol = n0 + wc*64 + n*16 + lr;
        const float v = (acc[m][n][r] + bias[fcol]) * scale;
        const unsigned short ov = f2bf(v);
        const int i = rr >> 1, bsel = rr & 1;
        const int h = fcol >> 6, d = fcol & 63;
        const int hh = bsel*NH + h;
        if (z == 0)      Qb [((size_t)hh*S_LEN + i)*HD + d] = ov;
        else if (z == 1) Kb [((size_t)hh*S_LEN + i)*HD + d] = ov;
        else             Vtb[((size_t)hh*HD + d)*S_LEN + i] = ov;
      }
}

// ---------------- QKV projection, fp32 A (small-ws fallback) ------------
__global__ __launch_bounds__(256) void k_qkv(
    const float* __restrict__ xA, int a_rs, int ishift,
    const float* __restrict__ wq, const float* __restrict__ wk,
    const float* __restrict__ wv,
    const float* __restrict__ bq, const float* __restrict__ bk,
    const float* __restrict__ bv,
    unsigned short* __restrict__ Qb, unsigned short* __restrict__ Kb,
    unsigned short* __restrict__ Vtb)
{
  __shared__ unsigned short Al[128*32];
  __shared__ unsigned short Bl[128*32];
  const int tid = threadIdx.x;
  const int z  = blockIdx.z;
  const int m0 = blockIdx.x * 128;
  const int n0 = blockIdx.y * 128;
  const int w = tid >> 6, lane = tid & 63;
  const int wr = w >> 1, wc = w & 1;
  const int lr = lane & 15, lhi = lane >> 4;
  const float* wz = (z==0) ? wq : ((z==1) ? wk : wv);

  f32x4 acc[4][4];
#pragma unroll
  for (int m=0;m<4;++m)
#pragma unroll
    for (int n=0;n<4;++n) acc[m][n] = (f32x4){0.f,0.f,0.f,0.f};

  for (int k0 = 0; k0 < EMB; k0 += 32) {
    float4 a0[2], a1[2], b0[2], b1[2];
#pragma unroll
    for (int j = 0; j < 2; ++j) {
      const int c   = j*256 + tid;
      const int row = c >> 2;
      const int col = (c & 3) << 3;
      const float* ap = xA + (size_t)(m0+row)*a_rs + k0 + col;
      const float* bp = wz + (size_t)(n0+row)*EMB + k0 + col;
      a0[j] = *(const float4*)ap;  a1[j] = *(const float4*)(ap+4);
      b0[j] = *(const float4*)bp;  b1[j] = *(const float4*)(bp+4);
    }
    __syncthreads();
#pragma unroll
    for (int j = 0; j < 2; ++j) {
      const int c   = j*256 + tid;
      const int row = c >> 2;
      const int col = (c & 3) << 3;
      *(ushort8*)&Al[row*32 + col] = cvt8(a0[j], a1[j]);
      *(ushort8*)&Bl[row*32 + col] = cvt8(b0[j], b1[j]);
    }
    __syncthreads();
    bf16x8 af[4], bfr[4];
#pragma unroll
    for (int m=0;m<4;++m) af[m]  = *(const bf16x8*)&Al[(wr*64 + m*16 + lr)*32 + lhi*8];
#pragma unroll
    for (int n=0;n<4;++n) bfr[n] = *(const bf16x8*)&Bl[(wc*64 + n*16 + lr)*32 + lhi*8];
#pragma unroll
    for (int m=0;m<4;++m)
#pragma unroll
      for (int n=0;n<4;++n)
        acc[m][n] = __builtin_amdgcn_mfma_f32_16x16x32_bf16(af[m], bfr[n], acc[m][n], 0,0,0);
  }

  const float scale = (z==0) ? 0.125f*LOG2E : 1.0f;
  const float* bias = (z==0) ? bq : ((z==1) ? bk : bv);
  const int bmask = (1 << ishift) - 1;
#pragma unroll
  for (int m=0;m<4;++m)
#pragma unroll
    for (int n=0;n<4;++n)
#pragma unroll
      for (int r=0;r<4;++r) {
        const int rr   = m0 + wr*64 + m*16 + lhi*4 + r;
        const int fcol = n0 + wc*64 + n*16 + lr;
        const float v = (acc[m][n][r] + bias[fcol]) * scale;
        const unsigned short ov = f2bf(v);
        const int i = rr >> ishift, bsel = rr & bmask;
        const int h = fcol >> 6, d = fcol & 63;
        const int hh = bsel*NH + h;
        if (z == 0)      Qb [((size_t)hh*S_LEN + i)*HD + d] = ov;
        else if (z == 1) Kb [((size_t)hh*S_LEN + i)*HD + d] = ov;
        else             Vtb[((size_t)hh*HD + d)*S_LEN + i] = ov;
      }
}

// ---------------- causal flash attention ----------------
__global__ __launch_bounds__(256,4) void k_attn(
    const unsigned short* __restrict__ Q,
    const unsigned short* __restrict__ K,
    const unsigned short* __restrict__ Vt,
    unsigned short* __restrict__ ctx, int bshift, int hsh)
{
  __shared__ unsigned short KL[2][64*64];
  __shared__ unsigned short VL[2][64*64];
  __shared__ unsigned short Pl[4][1024];

  const int tid = threadIdx.x;
  const int w = tid >> 6, lane = tid & 63;
  const int lr = lane & 15, lhi = lane >> 4;

  const int lin = blockIdx.x;
  const int cc  = lin >> hsh;
  const int chunk = (cc < 16) ? cc : (47 - cc);
  const int hh  = lin & ((1 << hsh) - 1);
  const int q0  = chunk*64 + w*16;

  const unsigned short* Qh = Q  + (size_t)hh*S_LEN*HD;
  const unsigned short* Kh = K  + (size_t)hh*S_LEN*HD;
  const unsigned short* Vh = Vt + (size_t)hh*HD*S_LEN;
  unsigned short* Pw = Pl[w];

  bf16x8 qf[2];
#pragma unroll
  for (int kf=0;kf<2;++kf)
    qf[kf] = *(const bf16x8*)&Qh[(size_t)(q0 + lr)*HD + kf*32 + lhi*8];

  f32x4 o[4];
  float rm = -3.0e38f, rl = 0.f;
#pragma unroll
  for (int dn=0;dn<4;++dn) o[dn] = (f32x4){0.f,0.f,0.f,0.f};

  const int tmax = chunk + 1;

  auto STAGE = [&](int tt, int bb2) {
    const int kv0 = tt*64;
#pragma unroll
    for (int j = 0; j < 2; ++j) {
      const int c   = j*256 + tid;
      const int row = c >> 3;
      const int sb  = (c*16) ^ ((row & 7) << 4);
      const int el  = (sb & 127) >> 1;
      const int ub  = (j*256 + (tid & 192)) * 16;
      GLOAD16(Kh + (size_t)(kv0+row)*HD + el,        (char*)KL[bb2] + ub);
      GLOAD16(Vh + (size_t)row*S_LEN + kv0 + el,     (char*)VL[bb2] + ub);
    }
  };

  STAGE(0, 0);
  int bb = 0;
  for (int t = 0; t < tmax; ++t) {
    if (t + 1 < tmax) {
      STAGE(t+1, bb^1);
      asm volatile("s_waitcnt vmcnt(4)" ::: "memory");
    } else {
      asm volatile("s_waitcnt vmcnt(0)" ::: "memory");
    }
    __builtin_amdgcn_s_barrier();

    const int kv0 = t*64;
    const char* KB = (const char*)KL[bb];
    const char* VB = (const char*)VL[bb];

    f32x4 st[4];
#pragma unroll
    for (int kn=0;kn<4;++kn) st[kn] = (f32x4){0.f,0.f,0.f,0.f};

    __builtin_amdgcn_s_setprio(1);
#pragma unroll
    for (int kn=0;kn<4;++kn)
#pragma unroll
      for (int kf=0;kf<2;++kf) {
        const int row = kn*16 + lr;
        const int byt = ((row<<7) + kf*64 + lhi*16) ^ ((row & 7) << 4);
        const bf16x8 kfr = *(const bf16x8*)(KB + byt);
        st[kn] = __builtin_amdgcn_mfma_f32_16x16x32_bf16(kfr, qf[kf], st[kn], 0,0,0);
      }
    __builtin_amdgcn_s_setprio(0);

    if (t == tmax-1) {
      const int q = q0 + lr;
#pragma unroll
      for (int kn=0;kn<4;++kn)
#pragma unroll
        for (int r=0;r<4;++r) {
          const int k = kv0 + kn*16 + lhi*4 + r;
          if (k > q) st[kn][r] = -1.0e30f;
        }
    }

    float mx = fmaxf(fmaxf(st[0][0], st[0][1]), fmaxf(st[0][2], st[0][3]));
#pragma unroll
    for (int kn=1;kn<4;++kn)
      mx = fmaxf(mx, fmaxf(fmaxf(st[kn][0], st[kn][1]),
                           fmaxf(st[kn][2], st[kn][3])));
    mx = fmaxf(mx, __shfl_xor(mx, 16));
    mx = fmaxf(mx, __shfl_xor(mx, 32));
    if (!__all(mx - rm <= 8.0f)) {
      const float newm  = fmaxf(rm, mx);
      const float alpha = exp2f(rm - newm);
      rl *= alpha;
#pragma unroll
      for (int dn=0;dn<4;++dn)
#pragma unroll
        for (int r=0;r<4;++r) o[dn][r] *= alpha;
      rm = newm;
    }
    float sum = 0.f;
#pragma unroll
    for (int kn=0;kn<4;++kn)
#pragma unroll
      for (int r=0;r<4;++r) {
        const float p = exp2f(st[kn][r] - rm);
        st[kn][r] = p;
        sum += p;
      }
    sum += __shfl_xor(sum, 16);
    sum += __shfl_xor(sum, 32);
    rl += sum;

    {
      const int qrow = lr;
#pragma unroll
      for (int kn=0;kn<4;++kn) {
        unsigned long long pk =
            (unsigned long long)f2bf(st[kn][0])
          | ((unsigned long long)f2bf(st[kn][1]) << 16)
          | ((unsigned long long)f2bf(st[kn][2]) << 32)
          | ((unsigned long long)f2bf(st[kn][3]) << 48);
        const int byt = (qrow*128 + kn*32 + lhi*8) ^ ((qrow & 7) << 4);
        *(unsigned long long*)((char*)Pw + byt) = pk;
      }
    }

#pragma unroll
    for (int ks=0;ks<2;++ks) {
      const int qrow = lr;
      const int pby = (qrow*128 + ks*64 + lhi*16) ^ ((qrow & 7) << 4);
      const bf16x8 pfr = *(const bf16x8*)((char*)Pw + pby);
      __builtin_amdgcn_s_setprio(1);
#pragma unroll
      for (int dn=0;dn<4;++dn) {
        const int row = dn*16 + lr;
        const int byt = ((row<<7) + ks*64 + lhi*16) ^ ((row & 7) << 4);
        const bf16x8 vf = *(const bf16x8*)(VB + byt);
        o[dn] = __builtin_amdgcn_mfma_f32_16x16x32_bf16(vf, pfr, o[dn], 0,0,0);
      }
      __builtin_amdgcn_s_setprio(0);
    }

    __builtin_amdgcn_s_barrier();
    bb ^= 1;
  }

  const int h = hh & (NH-1);
  const int badd = hh >> 4;
  const float inv = 1.0f / rl;
  const int q = q0 + lr;
  const size_t trow = ((size_t)q << bshift) + badd;
#pragma unroll
  for (int dn=0;dn<4;++dn) {
    unsigned long long pk =
        (unsigned long long)f2bf(o[dn][0]*inv)
      | ((unsigned long long)f2bf(o[dn][1]*inv) << 16)
      | ((unsigned long long)f2bf(o[dn][2]*inv) << 32)
      | ((unsigned long long)f2bf(o[dn][3]*inv) << 48);
    *(unsigned long long*)&ctx[trow*EMB + h*HD + dn*16 + lhi*4] = pk;
  }
}

// ---------------- output projection, bf16 A+B ----------------
__global__ __launch_bounds__(256) void k_oproj_bf(
    const unsigned short* __restrict__ ctxA,
    const unsigned short* __restrict__ wob,
    const float* __restrict__ bo,
    float* __restrict__ out)
{
  __shared__ unsigned short Al[128*32];
  __shared__ unsigned short Bl[128*32];
  const int tid = threadIdx.x;
  const int m0 = blockIdx.x * 128;
  const int n0 = blockIdx.y * 128;
  const int w = tid >> 6, lane = tid & 63;
  const int wr = w >> 1, wc = w & 1;
  const int lr = lane & 15, lhi = lane >> 4;

  f32x4 acc[4][4];
#pragma unroll
  for (int m=0;m<4;++m)
#pragma unroll
    for (int n=0;n<4;++n) acc[m][n] = (f32x4){0.f,0.f,0.f,0.f};

  for (int k0 = 0; k0 < EMB; k0 += 32) {
    __syncthreads();
#pragma unroll
    for (int j = 0; j < 2; ++j) {
      const int c   = j*256 + tid;
      const int row = c >> 2;
      const int col = (c & 3) << 3;
      const int ub  = (j*256 + (tid & 192)) * 16;
      GLOAD16(ctxA + (size_t)(m0+row)*EMB + k0 + col, (char*)Al + ub);
      GLOAD16(wob  + (size_t)(n0+row)*EMB + k0 + col, (char*)Bl + ub);
    }
    __syncthreads();
    bf16x8 af[4], bfr[4];
#pragma unroll
    for (int m=0;m<4;++m) af[m]  = *(const bf16x8*)&Al[(wr*64 + m*16 + lr)*32 + lhi*8];
#pragma unroll
    for (int n=0;n<4;++n) bfr[n] = *(const bf16x8*)&Bl[(wc*64 + n*16 + lr)*32 + lhi*8];
#pragma unroll
    for (int m=0;m<4;++m)
#pragma unroll
      for (int n=0;n<4;++n)
        acc[m][n] = __builtin_amdgcn_mfma_f32_16x16x32_bf16(af[m], bfr[n], acc[m][n], 0,0,0);
  }

#pragma unroll
  for (int m=0;m<4;++m)
#pragma unroll
    for (int n=0;n<4;++n)
#pragma unroll
      for (int r=0;r<4;++r) {
        const int rr   = m0 + wr*64 + m*16 + lhi*4 + r;
        const int fcol = n0 + wc*64 + n*16 + lr;
        out[(size_t)rr*EMB + fcol] = acc[m][n][r] + bo[fcol];
      }
}

// ---------------- output projection, fp32 B (fallback) -------------------
__global__ __launch_bounds__(256) void k_oproj(
    const unsigned short* __restrict__ ctxA,
    const float* __restrict__ wo,
    const float* __restrict__ bo,
    float* __restrict__ outb, int orm)
{
  __shared__ unsigned short Al[128*32];
  __shared__ unsigned short Bl[128*32];
  const int tid = threadIdx.x;
  const int m0 = blockIdx.x * 128;
  const int n0 = blockIdx.y * 128;
  const int w = tid >> 6, lane = tid & 63;
  const int wr = w >> 1, wc = w & 1;
  const int lr = lane & 15, lhi = lane >> 4;

  f32x4 acc[4][4];
#pragma unroll
  for (int m=0;m<4;++m)
#pragma unroll
    for (int n=0;n<4;++n) acc[m][n] = (f32x4){0.f,0.f,0.f,0.f};

  for (int k0 = 0; k0 < EMB; k0 += 32) {
    float4 b0[2], b1[2];
#pragma unroll
    for (int j = 0; j < 2; ++j) {
      const int c   = j*256 + tid;
      const int row = c >> 2;
      const int col = (c & 3) << 3;
      const float* bp = wo + (size_t)(n0+row)*EMB + k0 + col;
      b0[j] = *(const float4*)bp;  b1[j] = *(const float4*)(bp+4);
    }
    __syncthreads();
#pragma unroll
    for (int j = 0; j < 2; ++j) {
      const int c   = j*256 + tid;
      const int row = c >> 2;
      const int col = (c & 3) << 3;
      const int ub  = (j*256 + (tid & 192)) * 16;
      GLOAD16(ctxA + (size_t)(m0+row)*EMB + k0 + col, (char*)Al + ub);
      *(ushort8*)&Bl[row*32 + col] = cvt8(b0[j], b1[j]);
    }
    __syncthreads();
    bf16x8 af[4], bfr[4];
#pragma unroll
    for (int m=0;m<4;++m) af[m]  = *(const bf16x8*)&Al[(wr*64 + m*16 + lr)*32 + lhi*8];
#pragma unroll
    for (int n=0;n<4;++n) bfr[n] = *(const bf16x8*)&Bl[(wc*64 + n*16 + lr)*32 + lhi*8];
#pragma unroll
    for (int m=0;m<4;++m)
#pragma unroll
      for (int n=0;n<4;++n)
        acc[m][n] = __builtin_amdgcn_mfma_f32_16x16x32_bf16(af[m], bfr[n], acc[m][n], 0,0,0);
  }

#pragma unroll
  for (int m=0;m<4;++m)
#pragma unroll
    for (int n=0;n<4;++n)
#pragma unroll
      for (int r=0;r<4;++r) {
        const int rr   = m0 + wr*64 + m*16 + lhi*4 + r;
        const int fcol = n0 + wc*64 + n*16 + lr;
        outb[(size_t)rr*orm*EMB + fcol] = acc[m][n][r] + bo[fcol];
      }
}

// ---------------- launch ----------------
extern "C" void kernel_launch(void* const* d_in, const int* in_sizes, int n_in,
                              void* d_out, int out_size, void* d_ws, size_t ws_size,
                              hipStream_t stream) {
  const float* x  = (const float*)d_in[0];
  const float* wq = (const float*)d_in[1];
  const float* bq = (const float*)d_in[2];
  const float* wk = (const float*)d_in[3];
  const float* bk = (const float*)d_in[4];
  const float* wv = (const float*)d_in[5];
  const float* bv = (const float*)d_in[6];
  const float* wo = (const float*)d_in[7];
  const float* bo = (const float*)d_in[8];
  float* out = (float*)d_out;

  char* ws = (char*)d_ws;
  const size_t MB = (size_t)1 << 20;

  if (ws_size >= 38*MB) {
    // full-bf16 tier: Q@0 K@8 Vt@16 | wb@24(6MB) xb@30(8MB) | cx@24 (post-qkv)
    unsigned short* Q   = (unsigned short*)(ws + 0*MB);
    unsigned short* K   = (unsigned short*)(ws + 8*MB);
    unsigned short* Vt  = (unsigned short*)(ws + 16*MB);
    unsigned short* wb  = (unsigned short*)(ws + 24*MB);
    unsigned short* xb  = (unsigned short*)(ws + 30*MB);
    unsigned short* cx  = (unsigned short*)(ws + 24*MB);  // wb+xb dead post-qkv
    unsigned short* wob = Vt;                             // Vt dead post-attn

    k_cvt<<<2048, 256, 0, stream>>>(x,  xb, (S_LEN*BATCH)*EMB);
    k_cvt<<<512,  256, 0, stream>>>(wq, wb + (size_t)0*EMB*EMB, EMB*EMB);
    k_cvt<<<512,  256, 0, stream>>>(wk, wb + (size_t)1*EMB*EMB, EMB*EMB);
    k_cvt<<<512,  256, 0, stream>>>(wv, wb + (size_t)2*EMB*EMB, EMB*EMB);
    k_qkv_bb<<<768, 256, 0, stream>>>(xb, wb, bq,bk,bv, Q, K, Vt);
    k_attn<<<1024, 256, 0, stream>>>(Q, K, Vt, cx, 1, 5);
    k_cvt<<<512, 256, 0, stream>>>(wo, wob, EMB*EMB);
    k_oproj_bf<<<dim3(32,8), 256, 0, stream>>>(cx, wob, bo, out);
  } else if (ws_size >= 32*MB) {
    unsigned short* Q   = (unsigned short*)(ws + 0*MB);
    unsigned short* K   = (unsigned short*)(ws + 8*MB);
    unsigned short* Vt  = (unsigned short*)(ws + 16*MB);
    unsigned short* cx  = (unsigned short*)(ws + 24*MB);
    unsigned short* xb  = cx;        // dead before attn writes cx
    unsigned short* wob = Vt;        // Vt dead after attn

    k_cvt<<<2048, 256, 0, stream>>>(x, xb, (S_LEN*BATCH)*EMB);
    k_qkv_bf<<<768, 256, 0, stream>>>(xb, wq,wk,wv, bq,bk,bv, Q, K, Vt);
    k_attn<<<1024, 256, 0, stream>>>(Q, K, Vt, cx, 1, 5);
    k_cvt<<<512, 256, 0, stream>>>(wo, wob, EMB*EMB);
    k_oproj_bf<<<dim3(32,8), 256, 0, stream>>>(cx, wob, bo, out);
  } else {
    unsigned short* Q  = (unsigned short*)(ws + 0*MB);
    unsigned short* K  = (unsigned short*)(ws + 4*MB);
    unsigned short* Vt = (unsigned short*)(ws + 8*MB);
    unsigned short* cx = (unsigned short*)(ws + 12*MB);
    for (int b = 0; b < 2; ++b) {
      k_qkv<<<dim3(16,8,3), 256, 0, stream>>>(x + b*EMB, 2*EMB, 0,
                                              wq,wk,wv, bq,bk,bv, Q,K,Vt);
      k_attn<<<512, 256, 0, stream>>>(Q, K, Vt, cx, 0, 4);
      k_oproj<<<dim3(16,8), 256, 0, stream>>>(cx, wo, bo, out + b*EMB, 2);
    }
  }
}